// Round 5
// baseline (37243.866 us; speedup 1.0000x reference)
//
#include <hip/hip_runtime.h>
#include <cstdint>

#define EPS 1e-5
typedef signed char i8;

// ---------------------------------------------------------------------------
// BN param prep (f64): scale = g/sqrt(v+eps), shift = b - m*scale
// ---------------------------------------------------------------------------
__global__ void bn_prep(const float* __restrict__ g, const float* __restrict__ b,
                        const float* __restrict__ m, const float* __restrict__ v,
                        double* __restrict__ scale, double* __restrict__ shift, int C) {
    int i = blockIdx.x * blockDim.x + threadIdx.x;
    if (i < C) {
        double inv = (double)g[i] / sqrt((double)v[i] + EPS);
        scale[i] = inv;
        shift[i] = (double)b[i] - (double)m[i] * inv;
    }
}

__global__ void zero_out(float* __restrict__ out, int n) {
    int i = blockIdx.x * blockDim.x + threadIdx.x;
    if (i < n) out[i] = 0.f;
}

// ---------------------------------------------------------------------------
// Weight prep: wi8[o][tap][c] = sign(w[o][c][tap]) i8; alpha[o]=mean|w[o]| f64
// ---------------------------------------------------------------------------
template<int C>
__global__ void prep_w_i8(const float* __restrict__ w, i8* __restrict__ wi8,
                          double* __restrict__ alpha) {
    const int o = blockIdx.x;
    const int t = threadIdx.x;   // 256 threads
    const float* wo = w + (size_t)o * C * 9;

    double s = 0.0;
    for (int k = t; k < C * 9; k += 256) s += fabs((double)wo[k]);
    __shared__ double red[256];
    red[t] = s;
    __syncthreads();
    for (int r = 128; r > 0; r >>= 1) {
        if (t < r) red[t] += red[t + r];
        __syncthreads();
    }
    if (t == 0) alpha[o] = red[0] / (double)(C * 9);

    for (int e = t; e < 9 * C; e += 256) {
        int tap = e / C, c = e % C;
        float wv = wo[c * 9 + tap];
        wi8[((size_t)o * 9 + tap) * C + c] = (i8)((wv > 0.f) - (wv < 0.f));
    }
}

// ---------------------------------------------------------------------------
// Layer 0: real conv 3->128 (pad 1) in f64 + BN(f64) + sign -> i8 NHWC chunk
// blockDim = 64 (one wave). grid: (y=32, og=2, nc). Each lane = one out ch.
// ---------------------------------------------------------------------------
__global__ void conv0_sign(const float* __restrict__ x,
                           const float* __restrict__ w0,
                           const double* __restrict__ scale, const double* __restrict__ shift,
                           i8* __restrict__ a1, int n0) {
    const int lane = threadIdx.x;
    const int y = blockIdx.x;
    const int og = blockIdx.y;
    const int n = blockIdx.z;           // local chunk index
    const int o = og * 64 + lane;

    double wreg[27];
    const float* wo = w0 + o * 27;
#pragma unroll
    for (int k = 0; k < 27; ++k) wreg[k] = (double)wo[k];
    const double sc = scale[o], sh = shift[o];
    const float* xn = x + (size_t)(n0 + n) * 3 * 32 * 32;

    for (int xx = 0; xx < 32; ++xx) {
        double acc = 0.0;
#pragma unroll
        for (int c = 0; c < 3; ++c) {
#pragma unroll
            for (int dy = 0; dy < 3; ++dy) {
                int yy = y + dy - 1;
                if (yy < 0 || yy > 31) continue;
#pragma unroll
                for (int dx = 0; dx < 3; ++dx) {
                    int xs = xx + dx - 1;
                    if (xs < 0 || xs > 31) continue;
                    acc += wreg[(c * 3 + dy) * 3 + dx] * (double)xn[(c * 32 + yy) * 32 + xs];
                }
            }
        }
        double val = acc * sc + sh;
        a1[((size_t)((n * 32 + y) * 32 + xx)) * 128 + o] =
            (i8)((val > 0.0) - (val < 0.0));
    }
}

// ---------------------------------------------------------------------------
// i8 binconv: exact integer dot (signs), pad taps skipped, optional 2x2 pool
// of raw conv sums (alpha>0, g=1 => scale>0: max commutes), then f64 BN and
// either sign-i8 out (NHWC) or htanh f64 out (NCHW order for FC).
// One WAVE per output element (n, o, oy, ox); 64 lanes split channels.
// ---------------------------------------------------------------------------
template<int CIN, bool POOL, bool OUTF64>
__global__ void binconv_i8(const i8* __restrict__ a_in, const i8* __restrict__ wi8,
                           const double* __restrict__ alpha,
                           const double* __restrict__ scale, const double* __restrict__ shift,
                           i8* __restrict__ a_out, double* __restrict__ h5,
                           int H, int W, int O) {
    const int wave = threadIdx.x >> 6, lane = threadIdx.x & 63;
    const int Ho = POOL ? H / 2 : H, Wo = POOL ? W / 2 : W;
    long gid = (long)blockIdx.x * 4 + wave;
    const int ox = (int)(gid % Wo); gid /= Wo;
    const int oy = (int)(gid % Ho); gid /= Ho;
    const int o  = (int)(gid % O);  gid /= O;
    const int n  = (int)gid;        // local chunk index

    const i8* an = a_in + (size_t)n * H * W * CIN;
    const i8* wo = wi8 + (size_t)o * 9 * CIN;

    int vmax = -0x7FFFFFFF;
    const int PY = POOL ? 2 : 1;
#pragma unroll
    for (int py = 0; py < PY; ++py) {
#pragma unroll
        for (int px = 0; px < PY; ++px) {
            const int cy = POOL ? oy * 2 + py : oy;
            const int cx = POOL ? ox * 2 + px : ox;
            int acc = 0;
#pragma unroll
            for (int dy = 0; dy < 3; ++dy) {
                const int yy = cy + dy - 1;
                if (yy < 0 || yy >= H) continue;
#pragma unroll
                for (int dx = 0; dx < 3; ++dx) {
                    const int xs = cx + dx - 1;
                    if (xs < 0 || xs >= W) continue;
                    const i8* ap = an + ((size_t)yy * W + xs) * CIN + lane;
                    const i8* wp = wo + (dy * 3 + dx) * CIN + lane;
#pragma unroll
                    for (int s = 0; s < CIN / 64; ++s)
                        acc += (int)ap[s * 64] * (int)wp[s * 64];
                }
            }
            // wave butterfly reduce (all lanes end with the full sum)
#pragma unroll
            for (int d = 32; d > 0; d >>= 1) acc += __shfl_xor(acc, d, 64);
            vmax = max(vmax, acc);
        }
    }
    // reference order: c = alpha * (int sum); pooled; t = c*scale + shift
    const double c = alpha[o] * (double)vmax;
    const double t = c * scale[o] + shift[o];
    if (lane == 0) {
        if (OUTF64) {
            h5[((size_t)n * O + o) * (Ho * Wo) + oy * Wo + ox] = fmin(1.0, fmax(-1.0, t));
        } else {
            a_out[(((size_t)n * Ho + oy) * Wo + ox) * O + o] = (i8)((t > 0.0) - (t < 0.0));
        }
    }
}

// ---------------------------------------------------------------------------
// FC (f64): out[n,10] = h5[n, 8192] @ fcw[10,8192]^T + fcb   (one block per n)
// ---------------------------------------------------------------------------
__global__ void fc_kernel(const double* __restrict__ h, const float* __restrict__ fcw,
                          const float* __restrict__ fcb, float* __restrict__ out) {
    const int n = blockIdx.x, t = threadIdx.x;
    double acc[10];
#pragma unroll
    for (int j = 0; j < 10; ++j) acc[j] = 0.0;
    const double* hn = h + (size_t)n * 8192;
    for (int k = t; k < 8192; k += 256) {
        double xv = hn[k];
#pragma unroll
        for (int j = 0; j < 10; ++j) acc[j] += xv * (double)fcw[j * 8192 + k];
    }
    __shared__ double red[10][256];
#pragma unroll
    for (int j = 0; j < 10; ++j) red[j][t] = acc[j];
    __syncthreads();
    for (int r = 128; r > 0; r >>= 1) {
        if (t < r) {
#pragma unroll
            for (int j = 0; j < 10; ++j) red[j][t] += red[j][t + r];
        }
        __syncthreads();
    }
    if (t < 10) out[n * 10 + t] = (float)(red[t][0] + (double)fcb[t]);
}

// ===========================================================================
extern "C" void kernel_launch(void* const* d_in, const int* in_sizes, int n_in,
                              void* d_out, int out_size, void* d_ws, size_t ws_size,
                              hipStream_t stream) {
    const float* X = (const float*)d_in[0];
    const float *Wt[6], *G[6], *Bb[6], *M[6], *V[6];
    for (int i = 0; i < 6; ++i) {
        Wt[i] = (const float*)d_in[1 + 5 * i];
        G[i]  = (const float*)d_in[2 + 5 * i];
        Bb[i] = (const float*)d_in[3 + 5 * i];
        M[i]  = (const float*)d_in[4 + 5 * i];
        V[i]  = (const float*)d_in[5 + 5 * i];
    }
    const float* fcw = (const float*)d_in[31];
    const float* fcb = (const float*)d_in[32];
    float* out = (float*)d_out;

    char* ws = (char*)d_ws;
    size_t off = 0;
    auto alloc = [&](size_t bytes) -> void* {
        void* p = ws + off;
        off = (off + bytes + 255) & ~(size_t)255;
        return p;
    };

    const int C[6] = {128, 128, 256, 256, 512, 512};

    // ---- workspace layout (~15.3 MB; known-safe: ws_size >= 18 MB) ----
    double *scale[6], *shift[6];
    for (int i = 0; i < 6; ++i) {
        scale[i] = (double*)alloc(C[i] * sizeof(double));
        shift[i] = (double*)alloc(C[i] * sizeof(double));
    }
    const int OA[5] = {128, 256, 256, 512, 512};
    double* alpha[5];
    for (int i = 0; i < 5; ++i) alpha[i] = (double*)alloc(OA[i] * sizeof(double));
    // sign weights: [O, 9, CIN] i8
    const size_t WIN[5] = {128ull * 9 * 128, 256ull * 9 * 128, 256ull * 9 * 256,
                           512ull * 9 * 256, 512ull * 9 * 512};
    i8* wi8[5];
    for (int i = 0; i < 5; ++i) wi8[i] = (i8*)alloc(WIN[i]);
    // chunk activation buffers (NC = 32 images per chunk)
    const int NC = 32;
    i8* a1 = (i8*)alloc((size_t)NC * 32 * 32 * 128);
    i8* a2 = (i8*)alloc((size_t)NC * 16 * 16 * 128);
    i8* a3 = (i8*)alloc((size_t)NC * 16 * 16 * 256);
    i8* a4 = (i8*)alloc((size_t)NC * 8 * 8 * 256);
    i8* a5 = (i8*)alloc((size_t)NC * 8 * 8 * 512);
    double* h5c = (double*)alloc((size_t)NC * 8192 * sizeof(double));

    if (off > ws_size) {   // should never trigger (ws >= 18 MB established)
        zero_out<<<dim3((out_size + 255) / 256), dim3(256), 0, stream>>>(out, out_size);
        return;
    }

    // ---- one-time preps ----
    for (int i = 0; i < 6; ++i)
        bn_prep<<<dim3((C[i] + 255) / 256), dim3(256), 0, stream>>>(
            G[i], Bb[i], M[i], V[i], scale[i], shift[i], C[i]);

    prep_w_i8<128><<<dim3(128), dim3(256), 0, stream>>>(Wt[1], wi8[0], alpha[0]);
    prep_w_i8<128><<<dim3(256), dim3(256), 0, stream>>>(Wt[2], wi8[1], alpha[1]);
    prep_w_i8<256><<<dim3(256), dim3(256), 0, stream>>>(Wt[3], wi8[2], alpha[2]);
    prep_w_i8<256><<<dim3(512), dim3(256), 0, stream>>>(Wt[4], wi8[3], alpha[3]);
    prep_w_i8<512><<<dim3(512), dim3(256), 0, stream>>>(Wt[5], wi8[4], alpha[4]);

    // ---- batch-chunked pipeline ----
    for (int c = 0; c < 256 / NC; ++c) {
        const int n0 = c * NC;
        conv0_sign<<<dim3(32, 2, NC), dim3(64), 0, stream>>>(
            X, Wt[0], scale[0], shift[0], a1, n0);
        // L1: 128->128, 32x32, pool -> a2 (16x16)
        binconv_i8<128, true, false><<<dim3(NC * 128 * 16 * 16 / 4), dim3(256), 0, stream>>>(
            a1, wi8[0], alpha[0], scale[1], shift[1], a2, nullptr, 32, 32, 128);
        // L2: 128->256, 16x16 -> a3
        binconv_i8<128, false, false><<<dim3(NC * 256 * 16 * 16 / 4), dim3(256), 0, stream>>>(
            a2, wi8[1], alpha[1], scale[2], shift[2], a3, nullptr, 16, 16, 256);
        // L3: 256->256, 16x16, pool -> a4 (8x8)
        binconv_i8<256, true, false><<<dim3(NC * 256 * 8 * 8 / 4), dim3(256), 0, stream>>>(
            a3, wi8[2], alpha[2], scale[3], shift[3], a4, nullptr, 16, 16, 256);
        // L4: 256->512, 8x8 -> a5
        binconv_i8<256, false, false><<<dim3(NC * 512 * 8 * 8 / 4), dim3(256), 0, stream>>>(
            a4, wi8[3], alpha[3], scale[4], shift[4], a5, nullptr, 8, 8, 512);
        // L5: 512->512, 8x8, pool -> h5c (4x4), htanh f64
        binconv_i8<512, true, true><<<dim3(NC * 512 * 4 * 4 / 4), dim3(256), 0, stream>>>(
            a5, wi8[4], alpha[4], scale[5], shift[5], nullptr, h5c, 8, 8, 512);
        // FC for this chunk
        fc_kernel<<<dim3(NC), dim3(256), 0, stream>>>(h5c, fcw, fcb, out + (size_t)n0 * 10);
    }
}

// Round 6
// 1157.369 us; speedup vs baseline: 32.1798x; 32.1798x over previous
//
#include <hip/hip_runtime.h>
#include <cstdint>

#define EPS 1e-5
typedef unsigned long long u64;

// ---------------------------------------------------------------------------
// BN param prep (f64): scale = g/sqrt(v+eps), shift = b - m*scale
// ---------------------------------------------------------------------------
__global__ void bn_prep(const float* __restrict__ g, const float* __restrict__ b,
                        const float* __restrict__ m, const float* __restrict__ v,
                        double* __restrict__ scale, double* __restrict__ shift, int C) {
    int i = blockIdx.x * blockDim.x + threadIdx.x;
    if (i < C) {
        double inv = (double)g[i] / sqrt((double)v[i] + EPS);
        scale[i] = inv;
        shift[i] = (double)b[i] - (double)m[i] * inv;
    }
}

__global__ void zero_out(float* __restrict__ out, int n) {
    int i = blockIdx.x * blockDim.x + threadIdx.x;
    if (i < n) out[i] = 0.f;
}

// ---------------------------------------------------------------------------
// Weight prep: alpha[o] = mean|w[o]| in f64 (order matches round-5 exact run);
// wb[(o*9+tap)*W64+word] bit j = (w[o][word*64+j][tap] < 0)
// ---------------------------------------------------------------------------
template<int C>
__global__ void pack_w(const float* __restrict__ w, u64* __restrict__ wb,
                       double* __restrict__ alpha) {
    const int o = blockIdx.x;
    const int t = threadIdx.x;   // 256 threads
    const float* wo = w + (size_t)o * C * 9;

    double s = 0.0;
    for (int k = t; k < C * 9; k += 256) s += fabs((double)wo[k]);
    __shared__ double red[256];
    red[t] = s;
    __syncthreads();
    for (int r = 128; r > 0; r >>= 1) {
        if (t < r) red[t] += red[t + r];
        __syncthreads();
    }
    if (t == 0) alpha[o] = red[0] / (double)(C * 9);

    constexpr int W64 = C / 64;
    for (int e = t; e < 9 * W64; e += 256) {
        int tap = e / W64, word = e % W64;
        u64 bits = 0;
        for (int j = 0; j < 64; ++j) {
            int c = word * 64 + j;
            if (wo[c * 9 + tap] < 0.f) bits |= (1ull << j);
        }
        wb[((size_t)o * 9 + tap) * W64 + word] = bits;
    }
}

// ---------------------------------------------------------------------------
// Layer 0: real conv 3->128 (pad 1) in f64 + BN(f64) + sign -> bits [n,y,x,2]
// block 256 (4 waves); wave -> one y row; lane = out channel within group.
// grid: (8, 2, 256)
// ---------------------------------------------------------------------------
__global__ void conv0_pack(const float* __restrict__ x, const float* __restrict__ w0,
                           const double* __restrict__ scale, const double* __restrict__ shift,
                           u64* __restrict__ bits0) {
    const int wave = threadIdx.x >> 6, lane = threadIdx.x & 63;
    const int y = blockIdx.x * 4 + wave;
    const int og = blockIdx.y, n = blockIdx.z;
    const int o = og * 64 + lane;

    double wreg[27];
    const float* wo = w0 + o * 27;
#pragma unroll
    for (int k = 0; k < 27; ++k) wreg[k] = (double)wo[k];
    const double sc = scale[o], sh = shift[o];
    const float* xn = x + (size_t)n * 3 * 32 * 32;

    for (int xx = 0; xx < 32; ++xx) {
        double acc = 0.0;
#pragma unroll
        for (int c = 0; c < 3; ++c) {
#pragma unroll
            for (int dy = 0; dy < 3; ++dy) {
                const int yy = y + dy - 1;
                if (yy < 0 || yy > 31) continue;
#pragma unroll
                for (int dx = 0; dx < 3; ++dx) {
                    const int xs = xx + dx - 1;
                    if (xs < 0 || xs > 31) continue;
                    acc += wreg[(c * 3 + dy) * 3 + dx] * (double)xn[(c * 32 + yy) * 32 + xs];
                }
            }
        }
        const double val = acc * sc + sh;
        u64 b = __ballot(val < 0.0);
        if (lane == 0) bits0[((size_t)((n * 32 + y) * 32 + xx)) * 2 + og] = b;
    }
}

// ---------------------------------------------------------------------------
// Bit binconv: XNOR-popcount core, weights in VGPRs, f64 exact epilogue.
// lane = out channel (o = og*64+lane); wave = one output row (2 conv rows if
// POOL). dot = valid_bits - 2*popcount(xor); pool = int max in-lane; then
// t = (alpha*v)*scale + shift (f64, matches verified round-5 order).
// in bits: [n][y][x][W64IN]; out bits: [n][yo][xo][OGOUT]; LAST -> f32 h5 NCHW.
// grid: (rows/4, OGOUT, 256), block 256.
// ---------------------------------------------------------------------------
template<int H, int W, int W64IN, int OGOUT, bool POOL, bool LAST>
__global__ void bconv(const u64* __restrict__ in_bits, const u64* __restrict__ wb,
                      const double* __restrict__ alpha, const double* __restrict__ scale,
                      const double* __restrict__ shift, u64* __restrict__ out_bits,
                      float* __restrict__ h5) {
    const int wave = threadIdx.x >> 6, lane = threadIdx.x & 63;
    const int og = blockIdx.y, n = blockIdx.z;
    const int o = og * 64 + lane;

    u64 wreg[9][W64IN];
    {
        const u64* wp = wb + (size_t)o * 9 * W64IN;
#pragma unroll
        for (int t = 0; t < 9; ++t)
#pragma unroll
            for (int k = 0; k < W64IN; ++k) wreg[t][k] = wp[t * W64IN + k];
    }
    const double al = alpha[o], sc = scale[o], sh = shift[o];
    const u64* ib = in_bits + (size_t)n * H * W * W64IN;

    auto cpos = [&](int cy, int cx) -> int {
        int pop = 0, vw = 0;
#pragma unroll
        for (int dy = 0; dy < 3; ++dy) {
            const int yy = cy + dy - 1;
            if (yy < 0 || yy >= H) continue;
#pragma unroll
            for (int dx = 0; dx < 3; ++dx) {
                const int xs = cx + dx - 1;
                if (xs < 0 || xs >= W) continue;
                vw += W64IN;
                const u64* p = ib + ((size_t)yy * W + xs) * W64IN;
#pragma unroll
                for (int k = 0; k < W64IN; ++k)
                    pop += (int)__popcll(p[k] ^ wreg[dy * 3 + dx][k]);
            }
        }
        return vw * 64 - 2 * pop;
    };

    if (POOL) {
        const int pr = blockIdx.x * 4 + wave;   // pooled row
        const int cy = pr * 2;
        for (int pcx = 0; pcx < W / 2; ++pcx) {
            const int cx = pcx * 2;
            int v = cpos(cy, cx);
            v = max(v, cpos(cy, cx + 1));
            v = max(v, cpos(cy + 1, cx));
            v = max(v, cpos(cy + 1, cx + 1));
            const double t = (al * (double)v) * sc + sh;
            if (LAST) {
                // h5 NCHW: [n][O][H/2][W/2], O = OGOUT*64
                h5[(((size_t)n * (OGOUT * 64) + o) * (H / 2) + pr) * (W / 2) + pcx] =
                    (float)fmin(1.0, fmax(-1.0, t));
            } else {
                u64 b = __ballot(t < 0.0);
                if (lane == 0)
                    out_bits[(((size_t)n * (H / 2) + pr) * (W / 2) + pcx) * OGOUT + og] = b;
            }
        }
    } else {
        const int r = blockIdx.x * 4 + wave;    // conv row
        for (int cx = 0; cx < W; ++cx) {
            const int v = cpos(r, cx);
            const double t = (al * (double)v) * sc + sh;
            u64 b = __ballot(t < 0.0);
            if (lane == 0)
                out_bits[(((size_t)n * H + r) * W + cx) * OGOUT + og] = b;
        }
    }
}

// ---------------------------------------------------------------------------
// FC (f64 accumulate, f32 h5): out[n,10] = h5[n,8192] @ fcw^T + fcb
// ---------------------------------------------------------------------------
__global__ void fc_kernel(const float* __restrict__ h, const float* __restrict__ fcw,
                          const float* __restrict__ fcb, float* __restrict__ out) {
    const int n = blockIdx.x, t = threadIdx.x;
    double acc[10];
#pragma unroll
    for (int j = 0; j < 10; ++j) acc[j] = 0.0;
    const float* hn = h + (size_t)n * 8192;
    for (int k = t; k < 8192; k += 256) {
        double xv = (double)hn[k];
#pragma unroll
        for (int j = 0; j < 10; ++j) acc[j] += xv * (double)fcw[j * 8192 + k];
    }
    __shared__ double red[10][256];
#pragma unroll
    for (int j = 0; j < 10; ++j) red[j][t] = acc[j];
    __syncthreads();
    for (int r = 128; r > 0; r >>= 1) {
        if (t < r) {
#pragma unroll
            for (int j = 0; j < 10; ++j) red[j][t] += red[j][t + r];
        }
        __syncthreads();
    }
    if (t < 10) out[n * 10 + t] = (float)(red[t][0] + (double)fcb[t]);
}

// ===========================================================================
extern "C" void kernel_launch(void* const* d_in, const int* in_sizes, int n_in,
                              void* d_out, int out_size, void* d_ws, size_t ws_size,
                              hipStream_t stream) {
    const float* X = (const float*)d_in[0];
    const float *Wt[6], *G[6], *Bb[6], *M[6], *V[6];
    for (int i = 0; i < 6; ++i) {
        Wt[i] = (const float*)d_in[1 + 5 * i];
        G[i]  = (const float*)d_in[2 + 5 * i];
        Bb[i] = (const float*)d_in[3 + 5 * i];
        M[i]  = (const float*)d_in[4 + 5 * i];
        V[i]  = (const float*)d_in[5 + 5 * i];
    }
    const float* fcw = (const float*)d_in[31];
    const float* fcb = (const float*)d_in[32];
    float* out = (float*)d_out;

    char* ws = (char*)d_ws;
    size_t off = 0;
    auto alloc = [&](size_t bytes) -> void* {
        void* p = ws + off;
        off = (off + bytes + 255) & ~(size_t)255;
        return p;
    };

    const int C[6] = {128, 128, 256, 256, 512, 512};

    // ---- workspace (~17.9 MB total; known-safe: ws_size >= 18e6) ----
    double *scale[6], *shift[6];
    for (int i = 0; i < 6; ++i) {
        scale[i] = (double*)alloc(C[i] * sizeof(double));
        shift[i] = (double*)alloc(C[i] * sizeof(double));
    }
    const int OA[5] = {128, 256, 256, 512, 512};
    double* alpha[5];
    for (int i = 0; i < 5; ++i) alpha[i] = (double*)alloc(OA[i] * sizeof(double));
    const size_t WBN[5] = {128ull * 9 * 2, 256ull * 9 * 2, 256ull * 9 * 4,
                           512ull * 9 * 4, 512ull * 9 * 8};
    u64* wb[5];
    for (int i = 0; i < 5; ++i) wb[i] = (u64*)alloc(WBN[i] * sizeof(u64));
    u64* bits0 = (u64*)alloc(256ull * 32 * 32 * 2 * sizeof(u64));
    u64* bits1 = (u64*)alloc(256ull * 16 * 16 * 2 * sizeof(u64));
    u64* bits2 = (u64*)alloc(256ull * 16 * 16 * 4 * sizeof(u64));
    u64* bits3 = (u64*)alloc(256ull * 8 * 8 * 4 * sizeof(u64));
    u64* bits4 = (u64*)alloc(256ull * 8 * 8 * 8 * sizeof(u64));
    float* h5  = (float*)alloc(256ull * 8192 * sizeof(float));

    if (off > ws_size) {
        zero_out<<<dim3((out_size + 255) / 256), dim3(256), 0, stream>>>(out, out_size);
        return;
    }

    // ---- preps ----
    for (int i = 0; i < 6; ++i)
        bn_prep<<<dim3((C[i] + 255) / 256), dim3(256), 0, stream>>>(
            G[i], Bb[i], M[i], V[i], scale[i], shift[i], C[i]);

    pack_w<128><<<dim3(128), dim3(256), 0, stream>>>(Wt[1], wb[0], alpha[0]);
    pack_w<128><<<dim3(256), dim3(256), 0, stream>>>(Wt[2], wb[1], alpha[1]);
    pack_w<256><<<dim3(256), dim3(256), 0, stream>>>(Wt[3], wb[2], alpha[2]);
    pack_w<256><<<dim3(512), dim3(256), 0, stream>>>(Wt[4], wb[3], alpha[3]);
    pack_w<512><<<dim3(512), dim3(256), 0, stream>>>(Wt[5], wb[4], alpha[4]);

    // ---- conv0 (f64 exact) ----
    conv0_pack<<<dim3(8, 2, 256), dim3(256), 0, stream>>>(X, Wt[0], scale[0], shift[0], bits0);

    // ---- binconv chain (bit core, f64 epilogue) ----
    // L1: 128->128, 32x32, pool -> bits1 (16x16, OG=2)
    bconv<32, 32, 2, 2, true, false><<<dim3(4, 2, 256), dim3(256), 0, stream>>>(
        bits0, wb[0], alpha[0], scale[1], shift[1], bits1, nullptr);
    // L2: 128->256, 16x16 -> bits2 (OG=4)
    bconv<16, 16, 2, 4, false, false><<<dim3(4, 4, 256), dim3(256), 0, stream>>>(
        bits1, wb[1], alpha[1], scale[2], shift[2], bits2, nullptr);
    // L3: 256->256, 16x16, pool -> bits3 (8x8, OG=4)
    bconv<16, 16, 4, 4, true, false><<<dim3(2, 4, 256), dim3(256), 0, stream>>>(
        bits2, wb[2], alpha[2], scale[3], shift[3], bits3, nullptr);
    // L4: 256->512, 8x8 -> bits4 (OG=8)
    bconv<8, 8, 4, 8, false, false><<<dim3(2, 8, 256), dim3(256), 0, stream>>>(
        bits3, wb[3], alpha[3], scale[4], shift[4], bits4, nullptr);
    // L5: 512->512, 8x8, pool -> h5 (4x4 f32, NCHW)
    bconv<8, 8, 8, 8, true, true><<<dim3(1, 8, 256), dim3(256), 0, stream>>>(
        bits4, wb[4], alpha[4], scale[5], shift[5], nullptr, h5);

    // ---- FC ----
    fc_kernel<<<dim3(256), dim3(256), 0, stream>>>(h5, fcw, fcb, out);
}

// Round 7
// 855.392 us; speedup vs baseline: 43.5401x; 1.3530x over previous
//
#include <hip/hip_runtime.h>
#include <cstdint>

#define EPS 1e-5
typedef unsigned long long u64;
typedef unsigned int u32;

// ---------------------------------------------------------------------------
// BN param prep (f64): scale = g/sqrt(v+eps), shift = b - m*scale
// ---------------------------------------------------------------------------
__global__ void bn_prep(const float* __restrict__ g, const float* __restrict__ b,
                        const float* __restrict__ m, const float* __restrict__ v,
                        double* __restrict__ scale, double* __restrict__ shift, int C) {
    int i = blockIdx.x * blockDim.x + threadIdx.x;
    if (i < C) {
        double inv = (double)g[i] / sqrt((double)v[i] + EPS);
        scale[i] = inv;
        shift[i] = (double)b[i] - (double)m[i] * inv;
    }
}

// A[o] = alpha[o]*scale[o]  (fused constant; <=3ulp vs reference op order,
// decision margins are ~1e-9 so f64 is provably safe)
__global__ void fuse_a(const double* __restrict__ alpha, const double* __restrict__ scale,
                       double* __restrict__ A, int C) {
    int i = blockIdx.x * blockDim.x + threadIdx.x;
    if (i < C) A[i] = alpha[i] * scale[i];
}

__global__ void zero_out(float* __restrict__ out, int n) {
    int i = blockIdx.x * blockDim.x + threadIdx.x;
    if (i < n) out[i] = 0.f;
}

// ---------------------------------------------------------------------------
// Weight prep: alpha[o] = mean|w[o]| (f64); wb[(o*9+tap)*W64+word] bit j =
// (w[o][word*64+j][tap] < 0)
// ---------------------------------------------------------------------------
template<int C>
__global__ void pack_w(const float* __restrict__ w, u64* __restrict__ wb,
                       double* __restrict__ alpha) {
    const int o = blockIdx.x;
    const int t = threadIdx.x;   // 256 threads
    const float* wo = w + (size_t)o * C * 9;

    double s = 0.0;
    for (int k = t; k < C * 9; k += 256) s += fabs((double)wo[k]);
    __shared__ double red[256];
    red[t] = s;
    __syncthreads();
    for (int r = 128; r > 0; r >>= 1) {
        if (t < r) red[t] += red[t + r];
        __syncthreads();
    }
    if (t == 0) alpha[o] = red[0] / (double)(C * 9);

    constexpr int W64 = C / 64;
    for (int e = t; e < 9 * W64; e += 256) {
        int tap = e / W64, word = e % W64;
        u64 bits = 0;
        for (int j = 0; j < 64; ++j) {
            int c = word * 64 + j;
            if (wo[c * 9 + tap] < 0.f) bits |= (1ull << j);
        }
        wb[((size_t)o * 9 + tap) * W64 + word] = bits;
    }
}

// ---------------------------------------------------------------------------
// Layer 0: real conv 3->128 (pad 1) in f64 + BN(f64) + sign -> bits [n,y,x,2]
// (proven exact in rounds 5/6)
// ---------------------------------------------------------------------------
__global__ void conv0_pack(const float* __restrict__ x, const float* __restrict__ w0,
                           const double* __restrict__ scale, const double* __restrict__ shift,
                           u64* __restrict__ bits0) {
    const int wave = threadIdx.x >> 6, lane = threadIdx.x & 63;
    const int y = blockIdx.x * 4 + wave;
    const int og = blockIdx.y, n = blockIdx.z;
    const int o = og * 64 + lane;

    double wreg[27];
    const float* wo = w0 + o * 27;
#pragma unroll
    for (int k = 0; k < 27; ++k) wreg[k] = (double)wo[k];
    const double sc = scale[o], sh = shift[o];
    const float* xn = x + (size_t)n * 3 * 32 * 32;

    for (int xx = 0; xx < 32; ++xx) {
        double acc = 0.0;
#pragma unroll
        for (int c = 0; c < 3; ++c) {
#pragma unroll
            for (int dy = 0; dy < 3; ++dy) {
                const int yy = y + dy - 1;
                if (yy < 0 || yy > 31) continue;
#pragma unroll
                for (int dx = 0; dx < 3; ++dx) {
                    const int xs = xx + dx - 1;
                    if (xs < 0 || xs > 31) continue;
                    acc += wreg[(c * 3 + dy) * 3 + dx] * (double)xn[(c * 32 + yy) * 32 + xs];
                }
            }
        }
        const double val = acc * sc + sh;
        u64 b = __ballot(val < 0.0);
        if (lane == 0) bits0[((size_t)((n * 32 + y) * 32 + xx)) * 2 + og] = b;
    }
}

// ---------------------------------------------------------------------------
// bconv, no pool: lane = output pixel; 3x3xW64 window in VGPRs; loop OPW
// out-channels; per-lane output-bit accumulation; u32 stores.
// grid: (OTOT/OPW, 256/IPB), block 256 (4 waves).
// ---------------------------------------------------------------------------
template<int H, int W, int W64, int OTOT, int OPW>
__global__ __launch_bounds__(256) void bconv_np(
        const u64* __restrict__ in_bits, const u64* __restrict__ wb,
        const double* __restrict__ A, const double* __restrict__ B,
        u32* __restrict__ out_bits) {
    const int wave = threadIdx.x >> 6, lane = threadIdx.x & 63;
    constexpr int WPI = (H * W) / 64;    // waves per image (4 or 1)
    constexpr int IPB = 4 / WPI;         // images per block
    const int img = blockIdx.y * IPB + (IPB == 1 ? 0 : wave);
    const int pw  = (IPB == 1 ? wave : 0);
    const int p = pw * 64 + lane;
    const int y = p / W, x = p % W;
    const int obase = blockIdx.x * OPW;

    const u64* ib = in_bits + (size_t)img * H * W * W64;
    u64 win[3][3][W64];
    bool tv[3][3];
    int nvalid = 0;
#pragma unroll
    for (int dy = 0; dy < 3; ++dy)
#pragma unroll
        for (int dx = 0; dx < 3; ++dx) {
            const int yy = y + dy - 1, xs = x + dx - 1;
            const bool ok = (yy >= 0 && yy < H && xs >= 0 && xs < W);
            tv[dy][dx] = ok;
            nvalid += ok ? 1 : 0;
            const u64* q = ib + ((size_t)yy * W + xs) * W64;
#pragma unroll
            for (int k = 0; k < W64; ++k) win[dy][dx][k] = ok ? q[k] : 0ull;
        }
    const int basev = nvalid * 64 * W64;

    u32 obuf[OPW / 32];
    u32 cur = 0;
    const u64* wp = wb + (size_t)obase * 9 * W64;
    for (int oc = 0; oc < OPW; ++oc) {
        const u64* wo = wp + (size_t)oc * 9 * W64;
        int pop = 0;
#pragma unroll
        for (int dy = 0; dy < 3; ++dy)
#pragma unroll
            for (int dx = 0; dx < 3; ++dx) {
                int tp = 0;
#pragma unroll
                for (int k = 0; k < W64; ++k)
                    tp += (int)__popcll(win[dy][dx][k] ^ wo[(dy * 3 + dx) * W64 + k]);
                pop += tv[dy][dx] ? tp : 0;
            }
        const int v = basev - 2 * pop;
        const double t = fma(A[obase + oc], (double)v, B[obase + oc]);
        cur |= (u32)(t < 0.0) << (oc & 31);
        if ((oc & 31) == 31) { obuf[oc >> 5] = cur; cur = 0; }
    }
    u32* op = out_bits + ((size_t)img * H * W + (size_t)y * W + x) * (OTOT / 32) + (obase >> 5);
#pragma unroll
    for (int j = 0; j < OPW / 32; ++j) op[j] = obuf[j];
}

// ---------------------------------------------------------------------------
// bconv + 2x2 pool (bit out): lane = POOLED pixel; 4x4xW64 window; int max
// over 4 conv positions in-lane (exact: mul by alpha*scale>0 is monotonic).
// ---------------------------------------------------------------------------
template<int H, int W, int W64, int OTOT, int OPW>
__global__ __launch_bounds__(256) void bconv_pl(
        const u64* __restrict__ in_bits, const u64* __restrict__ wb,
        const double* __restrict__ A, const double* __restrict__ B,
        u32* __restrict__ out_bits) {
    const int wave = threadIdx.x >> 6, lane = threadIdx.x & 63;
    constexpr int Hp = H / 2, Wp = W / 2;
    constexpr int WPI = (Hp * Wp) / 64;  // 4 (L1) or 1 (L3)
    constexpr int IPB = 4 / WPI;
    const int img = blockIdx.y * IPB + (IPB == 1 ? 0 : wave);
    const int pw  = (IPB == 1 ? wave : 0);
    const int p = pw * 64 + lane;
    const int py = p / Wp, px = p % Wp;
    const int obase = blockIdx.x * OPW;

    const u64* ib = in_bits + (size_t)img * H * W * W64;
    u64 win[4][4][W64];
    bool wv[4][4];
#pragma unroll
    for (int wy = 0; wy < 4; ++wy)
#pragma unroll
        for (int wx = 0; wx < 4; ++wx) {
            const int yy = 2 * py - 1 + wy, xs = 2 * px - 1 + wx;
            const bool ok = (yy >= 0 && yy < H && xs >= 0 && xs < W);
            wv[wy][wx] = ok;
            const u64* q = ib + ((size_t)yy * W + xs) * W64;
#pragma unroll
            for (int k = 0; k < W64; ++k) win[wy][wx][k] = ok ? q[k] : 0ull;
        }
    int nv[2][2];
#pragma unroll
    for (int pp = 0; pp < 2; ++pp)
#pragma unroll
        for (int qq = 0; qq < 2; ++qq) {
            int c = 0;
#pragma unroll
            for (int dy = 0; dy < 3; ++dy)
#pragma unroll
                for (int dx = 0; dx < 3; ++dx) c += wv[pp + dy][qq + dx] ? 1 : 0;
            nv[pp][qq] = c * 64 * W64;
        }

    u32 obuf[OPW / 32];
    u32 cur = 0;
    const u64* wp = wb + (size_t)obase * 9 * W64;
    for (int oc = 0; oc < OPW; ++oc) {
        const u64* wo = wp + (size_t)oc * 9 * W64;
        int pop[2][2] = {{0, 0}, {0, 0}};
#pragma unroll
        for (int dy = 0; dy < 3; ++dy)
#pragma unroll
            for (int dx = 0; dx < 3; ++dx) {
                u64 wk[W64];
#pragma unroll
                for (int k = 0; k < W64; ++k) wk[k] = wo[(dy * 3 + dx) * W64 + k];
#pragma unroll
                for (int pp = 0; pp < 2; ++pp)
#pragma unroll
                    for (int qq = 0; qq < 2; ++qq) {
                        int tp = 0;
#pragma unroll
                        for (int k = 0; k < W64; ++k)
                            tp += (int)__popcll(win[pp + dy][qq + dx][k] ^ wk[k]);
                        pop[pp][qq] += wv[pp + dy][qq + dx] ? tp : 0;
                    }
            }
        int v = nv[0][0] - 2 * pop[0][0];
        v = max(v, nv[0][1] - 2 * pop[0][1]);
        v = max(v, nv[1][0] - 2 * pop[1][0]);
        v = max(v, nv[1][1] - 2 * pop[1][1]);
        const double t = fma(A[obase + oc], (double)v, B[obase + oc]);
        cur |= (u32)(t < 0.0) << (oc & 31);
        if ((oc & 31) == 31) { obuf[oc >> 5] = cur; cur = 0; }
    }
    u32* op = out_bits + ((size_t)img * Hp * Wp + (size_t)py * Wp + px) * (OTOT / 32) + (obase >> 5);
#pragma unroll
    for (int j = 0; j < OPW / 32; ++j) op[j] = obuf[j];
}

// ---------------------------------------------------------------------------
// L5: bconv + pool + htanh f32 out. lane = conv pixel (8x8=64); pool via 2
// shfl_xor on the int sums; 16 designated lanes store h5 NCHW.
// ---------------------------------------------------------------------------
template<int OPW>
__global__ __launch_bounds__(256) void bconv_last(
        const u64* __restrict__ in_bits, const u64* __restrict__ wb,
        const double* __restrict__ A, const double* __restrict__ B,
        float* __restrict__ h5) {
    constexpr int H = 8, W = 8, W64 = 8, OTOT = 512;
    const int wave = threadIdx.x >> 6, lane = threadIdx.x & 63;
    const int img = blockIdx.y * 4 + wave;
    const int y = lane >> 3, x = lane & 7;
    const int obase = blockIdx.x * OPW;

    const u64* ib = in_bits + (size_t)img * H * W * W64;
    u64 win[3][3][W64];
    bool tv[3][3];
    int nvalid = 0;
#pragma unroll
    for (int dy = 0; dy < 3; ++dy)
#pragma unroll
        for (int dx = 0; dx < 3; ++dx) {
            const int yy = y + dy - 1, xs = x + dx - 1;
            const bool ok = (yy >= 0 && yy < H && xs >= 0 && xs < W);
            tv[dy][dx] = ok;
            nvalid += ok ? 1 : 0;
            const u64* q = ib + ((size_t)yy * W + xs) * W64;
#pragma unroll
            for (int k = 0; k < W64; ++k) win[dy][dx][k] = ok ? q[k] : 0ull;
        }
    const int basev = nvalid * 64 * W64;
    const bool writer = ((lane & 1) == 0) && ((lane & 8) == 0);
    const int py = lane >> 4, px = (lane & 7) >> 1;

    const u64* wp = wb + (size_t)obase * 9 * W64;
    for (int oc = 0; oc < OPW; ++oc) {
        const u64* wo = wp + (size_t)oc * 9 * W64;
        int pop = 0;
#pragma unroll
        for (int dy = 0; dy < 3; ++dy)
#pragma unroll
            for (int dx = 0; dx < 3; ++dx) {
                int tp = 0;
#pragma unroll
                for (int k = 0; k < W64; ++k)
                    tp += (int)__popcll(win[dy][dx][k] ^ wo[(dy * 3 + dx) * W64 + k]);
                pop += tv[dy][dx] ? tp : 0;
            }
        const int v = basev - 2 * pop;
        int v2 = max(v, __shfl_xor(v, 1, 64));
        int v4 = max(v2, __shfl_xor(v2, 8, 64));
        const double t = fma(A[obase + oc], (double)v4, B[obase + oc]);
        const double hcl = fmin(1.0, fmax(-1.0, t));
        if (writer)
            h5[(((size_t)img * OTOT + obase + oc) * 4 + py) * 4 + px] = (float)hcl;
    }
}

// ---------------------------------------------------------------------------
// FC (f64 accumulate): out[n,10] = h5[n,8192] @ fcw^T + fcb
// ---------------------------------------------------------------------------
__global__ void fc_kernel(const float* __restrict__ h, const float* __restrict__ fcw,
                          const float* __restrict__ fcb, float* __restrict__ out) {
    const int n = blockIdx.x, t = threadIdx.x;
    double acc[10];
#pragma unroll
    for (int j = 0; j < 10; ++j) acc[j] = 0.0;
    const float* hn = h + (size_t)n * 8192;
    for (int k = t; k < 8192; k += 256) {
        double xv = (double)hn[k];
#pragma unroll
        for (int j = 0; j < 10; ++j) acc[j] += xv * (double)fcw[j * 8192 + k];
    }
    __shared__ double red[10][256];
#pragma unroll
    for (int j = 0; j < 10; ++j) red[j][t] = acc[j];
    __syncthreads();
    for (int r = 128; r > 0; r >>= 1) {
        if (t < r) {
#pragma unroll
            for (int j = 0; j < 10; ++j) red[j][t] += red[j][t + r];
        }
        __syncthreads();
    }
    if (t < 10) out[n * 10 + t] = (float)(red[t][0] + (double)fcb[t]);
}

// ===========================================================================
extern "C" void kernel_launch(void* const* d_in, const int* in_sizes, int n_in,
                              void* d_out, int out_size, void* d_ws, size_t ws_size,
                              hipStream_t stream) {
    const float* X = (const float*)d_in[0];
    const float *Wt[6], *G[6], *Bb[6], *M[6], *V[6];
    for (int i = 0; i < 6; ++i) {
        Wt[i] = (const float*)d_in[1 + 5 * i];
        G[i]  = (const float*)d_in[2 + 5 * i];
        Bb[i] = (const float*)d_in[3 + 5 * i];
        M[i]  = (const float*)d_in[4 + 5 * i];
        V[i]  = (const float*)d_in[5 + 5 * i];
    }
    const float* fcw = (const float*)d_in[31];
    const float* fcb = (const float*)d_in[32];
    float* out = (float*)d_out;

    char* ws = (char*)d_ws;
    size_t off = 0;
    auto alloc = [&](size_t bytes) -> void* {
        void* p = ws + off;
        off = (off + bytes + 255) & ~(size_t)255;
        return p;
    };

    const int C[6] = {128, 128, 256, 256, 512, 512};

    double *scale[6], *shift[6];
    for (int i = 0; i < 6; ++i) {
        scale[i] = (double*)alloc(C[i] * sizeof(double));
        shift[i] = (double*)alloc(C[i] * sizeof(double));
    }
    const int OA[5] = {128, 256, 256, 512, 512};
    double *alpha[5], *fA[5];
    for (int i = 0; i < 5; ++i) alpha[i] = (double*)alloc(OA[i] * sizeof(double));
    for (int i = 0; i < 5; ++i) fA[i] = (double*)alloc(OA[i] * sizeof(double));
    const size_t WBN[5] = {128ull * 9 * 2, 256ull * 9 * 2, 256ull * 9 * 4,
                           512ull * 9 * 4, 512ull * 9 * 8};
    u64* wb[5];
    for (int i = 0; i < 5; ++i) wb[i] = (u64*)alloc(WBN[i] * sizeof(u64));
    u64* bits0 = (u64*)alloc(256ull * 32 * 32 * 2 * sizeof(u64));
    u64* bits1 = (u64*)alloc(256ull * 16 * 16 * 2 * sizeof(u64));
    u64* bits2 = (u64*)alloc(256ull * 16 * 16 * 4 * sizeof(u64));
    u64* bits3 = (u64*)alloc(256ull * 8 * 8 * 4 * sizeof(u64));
    u64* bits4 = (u64*)alloc(256ull * 8 * 8 * 8 * sizeof(u64));
    float* h5  = (float*)alloc(256ull * 8192 * sizeof(float));

    if (off > ws_size) {
        zero_out<<<dim3((out_size + 255) / 256), dim3(256), 0, stream>>>(out, out_size);
        return;
    }

    // ---- preps ----
    for (int i = 0; i < 6; ++i)
        bn_prep<<<dim3((C[i] + 255) / 256), dim3(256), 0, stream>>>(
            G[i], Bb[i], M[i], V[i], scale[i], shift[i], C[i]);

    pack_w<128><<<dim3(128), dim3(256), 0, stream>>>(Wt[1], wb[0], alpha[0]);
    pack_w<128><<<dim3(256), dim3(256), 0, stream>>>(Wt[2], wb[1], alpha[1]);
    pack_w<256><<<dim3(256), dim3(256), 0, stream>>>(Wt[3], wb[2], alpha[2]);
    pack_w<256><<<dim3(512), dim3(256), 0, stream>>>(Wt[4], wb[3], alpha[3]);
    pack_w<512><<<dim3(512), dim3(256), 0, stream>>>(Wt[5], wb[4], alpha[4]);

    for (int i = 0; i < 5; ++i)
        fuse_a<<<dim3((OA[i] + 255) / 256), dim3(256), 0, stream>>>(
            alpha[i], scale[i + 1], fA[i], OA[i]);

    // ---- conv0 (f64 exact) ----
    conv0_pack<<<dim3(8, 2, 256), dim3(256), 0, stream>>>(X, Wt[0], scale[0], shift[0], bits0);

    // ---- binconv chain (lane=pixel bit core) ----
    // L1: 128->128, 32x32 pool -> bits1; OPW=64, grid (2,256)
    bconv_pl<32, 32, 2, 128, 64><<<dim3(2, 256), dim3(256), 0, stream>>>(
        bits0, wb[0], fA[0], shift[1], (u32*)bits1);
    // L2: 128->256, 16x16 -> bits2; OPW=128, grid (2,256)
    bconv_np<16, 16, 2, 256, 128><<<dim3(2, 256), dim3(256), 0, stream>>>(
        bits1, wb[1], fA[1], shift[2], (u32*)bits2);
    // L3: 256->256, 16x16 pool -> bits3; OPW=32, grid (8,64)
    bconv_pl<16, 16, 4, 256, 32><<<dim3(8, 64), dim3(256), 0, stream>>>(
        bits2, wb[2], fA[2], shift[3], (u32*)bits3);
    // L4: 256->512, 8x8 -> bits4; OPW=64, grid (8,64)
    bconv_np<8, 8, 4, 512, 64><<<dim3(8, 64), dim3(256), 0, stream>>>(
        bits3, wb[3], fA[3], shift[4], (u32*)bits4);
    // L5: 512->512, 8x8 pool -> h5 f32 NCHW; OPW=64, grid (8,64)
    bconv_last<64><<<dim3(8, 64), dim3(256), 0, stream>>>(
        bits4, wb[4], fA[4], shift[5], h5);

    // ---- FC ----
    fc_kernel<<<dim3(256), dim3(256), 0, stream>>>(h5, fcw, fcb, out);
}

// Round 8
// 650.785 us; speedup vs baseline: 57.2292x; 1.3144x over previous
//
#include <hip/hip_runtime.h>
#include <cstdint>

#define EPS 1e-5
typedef unsigned long long u64;
typedef unsigned int u32;

struct BnArgs { const float *g[6], *b[6], *m[6], *v[6]; };
struct PackArgs { const float* w[5]; u64* wb[5]; };

// ---------------------------------------------------------------------------
// Fused BN prep for all 6 layers: scale_all/shift_all flat, offsets
// {0,128,256,512,768,1280}, total 1792.
// ---------------------------------------------------------------------------
__global__ void bn_prep_all(BnArgs p, double* __restrict__ scale_all,
                            double* __restrict__ shift_all) {
    int i = blockIdx.x * 256 + threadIdx.x;
    if (i >= 1792) return;
    int l, base;
    if (i < 128)       { l = 0; base = 0; }
    else if (i < 256)  { l = 1; base = 128; }
    else if (i < 512)  { l = 2; base = 256; }
    else if (i < 768)  { l = 3; base = 512; }
    else if (i < 1280) { l = 4; base = 768; }
    else               { l = 5; base = 1280; }
    const int c = i - base;
    double inv = (double)p.g[l][c] / sqrt((double)p.v[l][c] + EPS);
    scale_all[i] = inv;
    shift_all[i] = (double)p.b[l][c] - (double)p.m[l][c] * inv;
}

__global__ void zero_out(float* __restrict__ out, int n) {
    int i = blockIdx.x * blockDim.x + threadIdx.x;
    if (i < n) out[i] = 0.f;
}

// ---------------------------------------------------------------------------
// Fused weight pack for all 5 binconv layers. blockIdx.x = global filter id:
// ranges {0,128,384,640,1152,1664}. Computes alpha (f64, same reduction order
// as verified rounds), fuses A = alpha*scale(BN l+1), packs sign bits.
// ---------------------------------------------------------------------------
__global__ void pack_all(PackArgs pk, const double* __restrict__ scale_all,
                         double* __restrict__ A_all) {
    const int ob = blockIdx.x;
    const int t = threadIdx.x;     // 256
    int l, base, Cin, bnoff;
    if (ob < 128)       { l = 0; base = 0;    Cin = 128; bnoff = 128; }
    else if (ob < 384)  { l = 1; base = 128;  Cin = 128; bnoff = 256; }
    else if (ob < 640)  { l = 2; base = 384;  Cin = 256; bnoff = 512; }
    else if (ob < 1152) { l = 3; base = 640;  Cin = 256; bnoff = 768; }
    else                { l = 4; base = 1152; Cin = 512; bnoff = 1280; }
    const int o = ob - base;
    const float* wo = pk.w[l] + (size_t)o * Cin * 9;

    double s = 0.0;
    for (int k = t; k < Cin * 9; k += 256) s += fabs((double)wo[k]);
    __shared__ double red[256];
    red[t] = s;
    __syncthreads();
    for (int r = 128; r > 0; r >>= 1) {
        if (t < r) red[t] += red[t + r];
        __syncthreads();
    }
    if (t == 0) {
        double alpha = red[0] / (double)(Cin * 9);
        A_all[ob] = alpha * scale_all[bnoff + o];
    }

    const int W64 = Cin / 64;
    u64* wb = pk.wb[l];
    for (int e = t; e < 9 * W64; e += 256) {
        int tap = e / W64, word = e % W64;
        u64 bits = 0;
        for (int j = 0; j < 64; ++j) {
            int c = word * 64 + j;
            if (wo[c * 9 + tap] < 0.f) bits |= (1ull << j);
        }
        wb[((size_t)o * 9 + tap) * W64 + word] = bits;
    }
}

// ---------------------------------------------------------------------------
// conv0 (f64 exact), lane = pixel: window (27 f64) in VGPRs; all 128 filters
// + BN consts staged in LDS; sign bits accumulated in-lane -> direct stores.
// grid: (4, 256), block 256. bits0 [n][y][x][2] u64.
// ---------------------------------------------------------------------------
__global__ __launch_bounds__(256) void conv0_pack(
        const float* __restrict__ x, const float* __restrict__ w0,
        const double* __restrict__ scale, const double* __restrict__ shift,
        u64* __restrict__ bits0) {
    __shared__ double wlds[128 * 27];
    __shared__ double sc[128], sh[128];
    const int tid = threadIdx.x;
    for (int e = tid; e < 128 * 27; e += 256) wlds[e] = (double)w0[e];
    for (int e = tid; e < 128; e += 256) { sc[e] = scale[e]; sh[e] = shift[e]; }
    __syncthreads();

    const int n = blockIdx.y;
    const int p = blockIdx.x * 256 + tid;        // 0..1023
    const int y = p >> 5, xx = p & 31;
    const float* xn = x + (size_t)n * 3 * 32 * 32;

    double win[27];
#pragma unroll
    for (int c = 0; c < 3; ++c)
#pragma unroll
        for (int dy = 0; dy < 3; ++dy)
#pragma unroll
            for (int dx = 0; dx < 3; ++dx) {
                const int yy = y + dy - 1, xs = xx + dx - 1;
                const bool ok = (yy >= 0 && yy < 32 && xs >= 0 && xs < 32);
                win[(c * 3 + dy) * 3 + dx] = ok ? (double)xn[(c * 32 + yy) * 32 + xs] : 0.0;
            }

    u64* op = bits0 + ((size_t)n * 1024 + p) * 2;
#pragma unroll
    for (int og = 0; og < 2; ++og) {
        u64 word = 0;
#pragma unroll 2
        for (int j = 0; j < 64; ++j) {
            const int o = og * 64 + j;
            const double* wo = &wlds[o * 27];
            double acc = 0.0;
#pragma unroll
            for (int k = 0; k < 27; ++k) acc = fma(wo[k], win[k], acc);
            const double val = acc * sc[o] + sh[o];
            word |= (u64)(val < 0.0) << j;
        }
        op[og] = word;
    }
}

// ---------------------------------------------------------------------------
// bconv, no pool: lane = output pixel; window in VGPRs; weights+A/B in LDS.
// ---------------------------------------------------------------------------
template<int H, int W, int W64, int OTOT, int OPW>
__global__ __launch_bounds__(256) void bconv_np(
        const u64* __restrict__ in_bits, const u64* __restrict__ wb,
        const double* __restrict__ A, const double* __restrict__ B,
        u32* __restrict__ out_bits) {
    const int tid = threadIdx.x;
    const int wave = tid >> 6, lane = tid & 63;
    constexpr int WPI = (H * W) / 64;
    constexpr int IPB = 4 / WPI;
    const int img = blockIdx.y * IPB + (IPB == 1 ? 0 : wave);
    const int pw  = (IPB == 1 ? wave : 0);
    const int p = pw * 64 + lane;
    const int y = p / W, x = p % W;
    const int obase = blockIdx.x * OPW;

    __shared__ u64 wlds[OPW * 9 * W64];
    __shared__ double Alds[OPW], Blds[OPW];
    {
        const u64* wg = wb + (size_t)obase * 9 * W64;
        for (int e = tid; e < OPW * 9 * W64; e += 256) wlds[e] = wg[e];
        for (int e = tid; e < OPW; e += 256) { Alds[e] = A[obase + e]; Blds[e] = B[obase + e]; }
    }
    __syncthreads();

    const u64* ib = in_bits + (size_t)img * H * W * W64;
    u64 win[3][3][W64];
    bool tv[3][3];
    int nvalid = 0;
#pragma unroll
    for (int dy = 0; dy < 3; ++dy)
#pragma unroll
        for (int dx = 0; dx < 3; ++dx) {
            const int yy = y + dy - 1, xs = x + dx - 1;
            const bool ok = (yy >= 0 && yy < H && xs >= 0 && xs < W);
            tv[dy][dx] = ok;
            nvalid += ok ? 1 : 0;
            const u64* q = ib + ((size_t)yy * W + xs) * W64;
#pragma unroll
            for (int k = 0; k < W64; ++k) win[dy][dx][k] = ok ? q[k] : 0ull;
        }
    const int basev = nvalid * 64 * W64;

    u32 obuf[OPW / 32];
    u32 cur = 0;
    for (int oc = 0; oc < OPW; ++oc) {
        const u64* wo = &wlds[oc * 9 * W64];
        int pop = 0;
#pragma unroll
        for (int dy = 0; dy < 3; ++dy)
#pragma unroll
            for (int dx = 0; dx < 3; ++dx) {
                int tp = 0;
#pragma unroll
                for (int k = 0; k < W64; ++k)
                    tp += (int)__popcll(win[dy][dx][k] ^ wo[(dy * 3 + dx) * W64 + k]);
                pop += tv[dy][dx] ? tp : 0;
            }
        const int v = basev - 2 * pop;
        const double t = fma(Alds[oc], (double)v, Blds[oc]);
        cur |= (u32)(t < 0.0) << (oc & 31);
        if ((oc & 31) == 31) { obuf[oc >> 5] = cur; cur = 0; }
    }
    u32* op = out_bits + ((size_t)img * H * W + (size_t)y * W + x) * (OTOT / 32) + (obase >> 5);
#pragma unroll
    for (int j = 0; j < OPW / 32; ++j) op[j] = obuf[j];
}

// ---------------------------------------------------------------------------
// bconv + 2x2 pool (bit out): lane = pooled pixel; 4x4 window; int max.
// ---------------------------------------------------------------------------
template<int H, int W, int W64, int OTOT, int OPW>
__global__ __launch_bounds__(256) void bconv_pl(
        const u64* __restrict__ in_bits, const u64* __restrict__ wb,
        const double* __restrict__ A, const double* __restrict__ B,
        u32* __restrict__ out_bits) {
    const int tid = threadIdx.x;
    const int wave = tid >> 6, lane = tid & 63;
    constexpr int Hp = H / 2, Wp = W / 2;
    constexpr int WPI = (Hp * Wp) / 64;
    constexpr int IPB = 4 / WPI;
    const int img = blockIdx.y * IPB + (IPB == 1 ? 0 : wave);
    const int pw  = (IPB == 1 ? wave : 0);
    const int p = pw * 64 + lane;
    const int py = p / Wp, px = p % Wp;
    const int obase = blockIdx.x * OPW;

    __shared__ u64 wlds[OPW * 9 * W64];
    __shared__ double Alds[OPW], Blds[OPW];
    {
        const u64* wg = wb + (size_t)obase * 9 * W64;
        for (int e = tid; e < OPW * 9 * W64; e += 256) wlds[e] = wg[e];
        for (int e = tid; e < OPW; e += 256) { Alds[e] = A[obase + e]; Blds[e] = B[obase + e]; }
    }
    __syncthreads();

    const u64* ib = in_bits + (size_t)img * H * W * W64;
    u64 win[4][4][W64];
    bool wv[4][4];
#pragma unroll
    for (int wy = 0; wy < 4; ++wy)
#pragma unroll
        for (int wx = 0; wx < 4; ++wx) {
            const int yy = 2 * py - 1 + wy, xs = 2 * px - 1 + wx;
            const bool ok = (yy >= 0 && yy < H && xs >= 0 && xs < W);
            wv[wy][wx] = ok;
            const u64* q = ib + ((size_t)yy * W + xs) * W64;
#pragma unroll
            for (int k = 0; k < W64; ++k) win[wy][wx][k] = ok ? q[k] : 0ull;
        }
    int nv[2][2];
#pragma unroll
    for (int pp = 0; pp < 2; ++pp)
#pragma unroll
        for (int qq = 0; qq < 2; ++qq) {
            int c = 0;
#pragma unroll
            for (int dy = 0; dy < 3; ++dy)
#pragma unroll
                for (int dx = 0; dx < 3; ++dx) c += wv[pp + dy][qq + dx] ? 1 : 0;
            nv[pp][qq] = c * 64 * W64;
        }

    u32 obuf[OPW / 32];
    u32 cur = 0;
    for (int oc = 0; oc < OPW; ++oc) {
        const u64* wo = &wlds[oc * 9 * W64];
        int pop[2][2] = {{0, 0}, {0, 0}};
#pragma unroll
        for (int dy = 0; dy < 3; ++dy)
#pragma unroll
            for (int dx = 0; dx < 3; ++dx) {
                u64 wk[W64];
#pragma unroll
                for (int k = 0; k < W64; ++k) wk[k] = wo[(dy * 3 + dx) * W64 + k];
#pragma unroll
                for (int pp = 0; pp < 2; ++pp)
#pragma unroll
                    for (int qq = 0; qq < 2; ++qq) {
                        int tp = 0;
#pragma unroll
                        for (int k = 0; k < W64; ++k)
                            tp += (int)__popcll(win[pp + dy][qq + dx][k] ^ wk[k]);
                        pop[pp][qq] += wv[pp + dy][qq + dx] ? tp : 0;
                    }
            }
        int v = nv[0][0] - 2 * pop[0][0];
        v = max(v, nv[0][1] - 2 * pop[0][1]);
        v = max(v, nv[1][0] - 2 * pop[1][0]);
        v = max(v, nv[1][1] - 2 * pop[1][1]);
        const double t = fma(Alds[oc], (double)v, Blds[oc]);
        cur |= (u32)(t < 0.0) << (oc & 31);
        if ((oc & 31) == 31) { obuf[oc >> 5] = cur; cur = 0; }
    }
    u32* op = out_bits + ((size_t)img * Hp * Wp + (size_t)py * Wp + px) * (OTOT / 32) + (obase >> 5);
#pragma unroll
    for (int j = 0; j < OPW / 32; ++j) op[j] = obuf[j];
}

// ---------------------------------------------------------------------------
// L5: bconv + pool + htanh f32. lane = conv pixel (8x8); pool via shfl_xor.
// ---------------------------------------------------------------------------
template<int OPW>
__global__ __launch_bounds__(256) void bconv_last(
        const u64* __restrict__ in_bits, const u64* __restrict__ wb,
        const double* __restrict__ A, const double* __restrict__ B,
        float* __restrict__ h5) {
    constexpr int H = 8, W = 8, W64 = 8, OTOT = 512;
    const int tid = threadIdx.x;
    const int wave = tid >> 6, lane = tid & 63;
    const int img = blockIdx.y * 4 + wave;
    const int y = lane >> 3, x = lane & 7;
    const int obase = blockIdx.x * OPW;

    __shared__ u64 wlds[OPW * 9 * W64];
    __shared__ double Alds[OPW], Blds[OPW];
    {
        const u64* wg = wb + (size_t)obase * 9 * W64;
        for (int e = tid; e < OPW * 9 * W64; e += 256) wlds[e] = wg[e];
        for (int e = tid; e < OPW; e += 256) { Alds[e] = A[obase + e]; Blds[e] = B[obase + e]; }
    }
    __syncthreads();

    const u64* ib = in_bits + (size_t)img * H * W * W64;
    u64 win[3][3][W64];
    bool tv[3][3];
    int nvalid = 0;
#pragma unroll
    for (int dy = 0; dy < 3; ++dy)
#pragma unroll
        for (int dx = 0; dx < 3; ++dx) {
            const int yy = y + dy - 1, xs = x + dx - 1;
            const bool ok = (yy >= 0 && yy < H && xs >= 0 && xs < W);
            tv[dy][dx] = ok;
            nvalid += ok ? 1 : 0;
            const u64* q = ib + ((size_t)yy * W + xs) * W64;
#pragma unroll
            for (int k = 0; k < W64; ++k) win[dy][dx][k] = ok ? q[k] : 0ull;
        }
    const int basev = nvalid * 64 * W64;
    const bool writer = ((lane & 1) == 0) && ((lane & 8) == 0);
    const int py = lane >> 4, px = (lane & 7) >> 1;

    for (int oc = 0; oc < OPW; ++oc) {
        const u64* wo = &wlds[oc * 9 * W64];
        int pop = 0;
#pragma unroll
        for (int dy = 0; dy < 3; ++dy)
#pragma unroll
            for (int dx = 0; dx < 3; ++dx) {
                int tp = 0;
#pragma unroll
                for (int k = 0; k < W64; ++k)
                    tp += (int)__popcll(win[dy][dx][k] ^ wo[(dy * 3 + dx) * W64 + k]);
                pop += tv[dy][dx] ? tp : 0;
            }
        const int v = basev - 2 * pop;
        int v2 = max(v, __shfl_xor(v, 1, 64));
        int v4 = max(v2, __shfl_xor(v2, 8, 64));
        const double t = fma(Alds[oc], (double)v4, Blds[oc]);
        const double hcl = fmin(1.0, fmax(-1.0, t));
        if (writer)
            h5[(((size_t)img * OTOT + obase + oc) * 4 + py) * 4 + px] = (float)hcl;
    }
}

// ---------------------------------------------------------------------------
// FC (f64 accumulate): out[n,10] = h5[n,8192] @ fcw^T + fcb
// ---------------------------------------------------------------------------
__global__ void fc_kernel(const float* __restrict__ h, const float* __restrict__ fcw,
                          const float* __restrict__ fcb, float* __restrict__ out) {
    const int n = blockIdx.x, t = threadIdx.x;
    double acc[10];
#pragma unroll
    for (int j = 0; j < 10; ++j) acc[j] = 0.0;
    const float* hn = h + (size_t)n * 8192;
    for (int k = t; k < 8192; k += 256) {
        double xv = (double)hn[k];
#pragma unroll
        for (int j = 0; j < 10; ++j) acc[j] += xv * (double)fcw[j * 8192 + k];
    }
    __shared__ double red[10][256];
#pragma unroll
    for (int j = 0; j < 10; ++j) red[j][t] = acc[j];
    __syncthreads();
    for (int r = 128; r > 0; r >>= 1) {
        if (t < r) {
#pragma unroll
            for (int j = 0; j < 10; ++j) red[j][t] += red[j][t + r];
        }
        __syncthreads();
    }
    if (t < 10) out[n * 10 + t] = (float)(red[t][0] + (double)fcb[t]);
}

// ===========================================================================
extern "C" void kernel_launch(void* const* d_in, const int* in_sizes, int n_in,
                              void* d_out, int out_size, void* d_ws, size_t ws_size,
                              hipStream_t stream) {
    const float* X = (const float*)d_in[0];
    BnArgs bn;
    PackArgs pk;
    const float* Wt0 = (const float*)d_in[1];
    for (int i = 0; i < 6; ++i) {
        bn.g[i] = (const float*)d_in[2 + 5 * i];
        bn.b[i] = (const float*)d_in[3 + 5 * i];
        bn.m[i] = (const float*)d_in[4 + 5 * i];
        bn.v[i] = (const float*)d_in[5 + 5 * i];
    }
    for (int i = 0; i < 5; ++i) pk.w[i] = (const float*)d_in[1 + 5 * (i + 1)];
    const float* fcw = (const float*)d_in[31];
    const float* fcb = (const float*)d_in[32];
    float* out = (float*)d_out;

    char* ws = (char*)d_ws;
    size_t off = 0;
    auto alloc = [&](size_t bytes) -> void* {
        void* p = ws + off;
        off = (off + bytes + 255) & ~(size_t)255;
        return p;
    };

    // ---- workspace ----
    double* scale_all = (double*)alloc(1792 * sizeof(double));
    double* shift_all = (double*)alloc(1792 * sizeof(double));
    double* A_all     = (double*)alloc(1664 * sizeof(double));
    const size_t WBN[5] = {128ull * 9 * 2, 256ull * 9 * 2, 256ull * 9 * 4,
                           512ull * 9 * 4, 512ull * 9 * 8};
    for (int i = 0; i < 5; ++i) pk.wb[i] = (u64*)alloc(WBN[i] * sizeof(u64));
    u64* bits0 = (u64*)alloc(256ull * 32 * 32 * 2 * sizeof(u64));
    u64* bits1 = (u64*)alloc(256ull * 16 * 16 * 2 * sizeof(u64));
    u64* bits2 = (u64*)alloc(256ull * 16 * 16 * 4 * sizeof(u64));
    u64* bits3 = (u64*)alloc(256ull * 8 * 8 * 4 * sizeof(u64));
    u64* bits4 = (u64*)alloc(256ull * 8 * 8 * 8 * sizeof(u64));
    float* h5  = (float*)alloc(256ull * 8192 * sizeof(float));

    if (off > ws_size) {
        zero_out<<<dim3((out_size + 255) / 256), dim3(256), 0, stream>>>(out, out_size);
        return;
    }

    // BN offsets: {0,128,256,512,768,1280}; A offsets: {0,128,384,640,1152}
    const int BOF[6] = {0, 128, 256, 512, 768, 1280};
    const int AOF[5] = {0, 128, 384, 640, 1152};

    // ---- preps (2 launches) ----
    bn_prep_all<<<dim3(7), dim3(256), 0, stream>>>(bn, scale_all, shift_all);
    pack_all<<<dim3(1664), dim3(256), 0, stream>>>(pk, scale_all, A_all);

    // ---- conv0 (f64 exact, lane=pixel) ----
    conv0_pack<<<dim3(4, 256), dim3(256), 0, stream>>>(
        X, Wt0, scale_all + BOF[0], shift_all + BOF[0], bits0);

    // ---- binconv chain ----
    bconv_pl<32, 32, 2, 128, 64><<<dim3(2, 256), dim3(256), 0, stream>>>(
        bits0, pk.wb[0], A_all + AOF[0], shift_all + BOF[1], (u32*)bits1);
    bconv_np<16, 16, 2, 256, 128><<<dim3(2, 256), dim3(256), 0, stream>>>(
        bits1, pk.wb[1], A_all + AOF[1], shift_all + BOF[2], (u32*)bits2);
    bconv_pl<16, 16, 4, 256, 32><<<dim3(8, 64), dim3(256), 0, stream>>>(
        bits2, pk.wb[2], A_all + AOF[2], shift_all + BOF[3], (u32*)bits3);
    bconv_np<8, 8, 4, 512, 64><<<dim3(8, 64), dim3(256), 0, stream>>>(
        bits3, pk.wb[3], A_all + AOF[3], shift_all + BOF[4], (u32*)bits4);
    bconv_last<64><<<dim3(8, 64), dim3(256), 0, stream>>>(
        bits4, pk.wb[4], A_all + AOF[4], shift_all + BOF[5], h5);

    // ---- FC ----
    fc_kernel<<<dim3(256), dim3(256), 0, stream>>>(h5, fcw, fcb, out);
}

// Round 9
// 608.576 us; speedup vs baseline: 61.1984x; 1.0694x over previous
//
#include <hip/hip_runtime.h>
#include <cstdint>

#define EPS 1e-5
typedef unsigned long long u64;
typedef unsigned int u32;

struct BnArgs { const float *g[6], *b[6], *m[6], *v[6]; };
struct PackArgs { const float* w[5]; u64* wb[5]; };

// ---------------------------------------------------------------------------
// Fused BN prep: offsets {0,128,256,512,768,1280}, total 1792.
// ---------------------------------------------------------------------------
__global__ void bn_prep_all(BnArgs p, double* __restrict__ scale_all,
                            double* __restrict__ shift_all) {
    int i = blockIdx.x * 256 + threadIdx.x;
    if (i >= 1792) return;
    int l, base;
    if (i < 128)       { l = 0; base = 0; }
    else if (i < 256)  { l = 1; base = 128; }
    else if (i < 512)  { l = 2; base = 256; }
    else if (i < 768)  { l = 3; base = 512; }
    else if (i < 1280) { l = 4; base = 768; }
    else               { l = 5; base = 1280; }
    const int c = i - base;
    double inv = (double)p.g[l][c] / sqrt((double)p.v[l][c] + EPS);
    scale_all[i] = inv;
    shift_all[i] = (double)p.b[l][c] - (double)p.m[l][c] * inv;
}

__global__ void zero_out(float* __restrict__ out, int n) {
    int i = blockIdx.x * blockDim.x + threadIdx.x;
    if (i < n) out[i] = 0.f;
}

// ---------------------------------------------------------------------------
// Fused weight pack for all 5 binconv layers; A = alpha*scale fused.
// ---------------------------------------------------------------------------
__global__ void pack_all(PackArgs pk, const double* __restrict__ scale_all,
                         double* __restrict__ A_all) {
    const int ob = blockIdx.x;
    const int t = threadIdx.x;
    int l, base, Cin, bnoff;
    if (ob < 128)       { l = 0; base = 0;    Cin = 128; bnoff = 128; }
    else if (ob < 384)  { l = 1; base = 128;  Cin = 128; bnoff = 256; }
    else if (ob < 640)  { l = 2; base = 384;  Cin = 256; bnoff = 512; }
    else if (ob < 1152) { l = 3; base = 640;  Cin = 256; bnoff = 768; }
    else                { l = 4; base = 1152; Cin = 512; bnoff = 1280; }
    const int o = ob - base;
    const float* wo = pk.w[l] + (size_t)o * Cin * 9;

    double s = 0.0;
    for (int k = t; k < Cin * 9; k += 256) s += fabs((double)wo[k]);
    __shared__ double red[256];
    red[t] = s;
    __syncthreads();
    for (int r = 128; r > 0; r >>= 1) {
        if (t < r) red[t] += red[t + r];
        __syncthreads();
    }
    if (t == 0) {
        double alpha = red[0] / (double)(Cin * 9);
        A_all[ob] = alpha * scale_all[bnoff + o];
    }

    const int W64 = Cin / 64;
    u64* wb = pk.wb[l];
    for (int e = t; e < 9 * W64; e += 256) {
        int tap = e / W64, word = e % W64;
        u64 bits = 0;
        for (int j = 0; j < 64; ++j) {
            int c = word * 64 + j;
            if (wo[c * 9 + tap] < 0.f) bits |= (1ull << j);
        }
        wb[((size_t)o * 9 + tap) * W64 + word] = bits;
    }
}

// ---------------------------------------------------------------------------
// conv0 (f64 exact), lane = pixel; filters+BN in LDS; in-lane bit packing.
// ---------------------------------------------------------------------------
__global__ __launch_bounds__(256) void conv0_pack(
        const float* __restrict__ x, const float* __restrict__ w0,
        const double* __restrict__ scale, const double* __restrict__ shift,
        u64* __restrict__ bits0) {
    __shared__ double wlds[128 * 27];
    __shared__ double sc[128], sh[128];
    const int tid = threadIdx.x;
    for (int e = tid; e < 128 * 27; e += 256) wlds[e] = (double)w0[e];
    for (int e = tid; e < 128; e += 256) { sc[e] = scale[e]; sh[e] = shift[e]; }
    __syncthreads();

    const int n = blockIdx.y;
    const int p = blockIdx.x * 256 + tid;
    const int y = p >> 5, xx = p & 31;
    const float* xn = x + (size_t)n * 3 * 32 * 32;

    double win[27];
#pragma unroll
    for (int c = 0; c < 3; ++c)
#pragma unroll
        for (int dy = 0; dy < 3; ++dy)
#pragma unroll
            for (int dx = 0; dx < 3; ++dx) {
                const int yy = y + dy - 1, xs = xx + dx - 1;
                const bool ok = (yy >= 0 && yy < 32 && xs >= 0 && xs < 32);
                win[(c * 3 + dy) * 3 + dx] = ok ? (double)xn[(c * 32 + yy) * 32 + xs] : 0.0;
            }

    u64* op = bits0 + ((size_t)n * 1024 + p) * 2;
#pragma unroll
    for (int og = 0; og < 2; ++og) {
        u64 word = 0;
#pragma unroll 2
        for (int j = 0; j < 64; ++j) {
            const int o = og * 64 + j;
            const double* wo = &wlds[o * 27];
            double acc = 0.0;
#pragma unroll
            for (int k = 0; k < 27; ++k) acc = fma(wo[k], win[k], acc);
            const double val = acc * sc[o] + sh[o];
            word |= (u64)(val < 0.0) << j;
        }
        op[og] = word;
    }
}

// ---------------------------------------------------------------------------
// bconv, no pool: lane = output pixel; 3x3 window in VGPRs; weights in LDS.
// MINW = min waves/EU (controls VGPR cap so the window stays resident).
// ---------------------------------------------------------------------------
template<int H, int W, int W64, int OTOT, int OPW, int MINW>
__global__ __launch_bounds__(256, MINW) void bconv_np(
        const u64* __restrict__ in_bits, const u64* __restrict__ wb,
        const double* __restrict__ A, const double* __restrict__ B,
        u32* __restrict__ out_bits) {
    const int tid = threadIdx.x;
    const int wave = tid >> 6, lane = tid & 63;
    constexpr int WPI = (H * W) / 64;
    constexpr int IPB = (WPI >= 4) ? 1 : 4 / WPI;
    const int img = (IPB == 1) ? blockIdx.y : blockIdx.y * IPB + wave;
    const int pw  = (IPB == 1) ? wave : 0;
    const int p = pw * 64 + lane;
    const int y = p / W, x = p % W;
    const int obase = blockIdx.x * OPW;

    __shared__ u64 wlds[OPW * 9 * W64];
    __shared__ double Alds[OPW], Blds[OPW];
    {
        const u64* wg = wb + (size_t)obase * 9 * W64;
        for (int e = tid; e < OPW * 9 * W64; e += 256) wlds[e] = wg[e];
        for (int e = tid; e < OPW; e += 256) { Alds[e] = A[obase + e]; Blds[e] = B[obase + e]; }
    }
    __syncthreads();

    const u64* ib = in_bits + (size_t)img * H * W * W64;
    u64 win[3][3][W64];
    bool tv[3][3];
    int nvalid = 0;
#pragma unroll
    for (int dy = 0; dy < 3; ++dy)
#pragma unroll
        for (int dx = 0; dx < 3; ++dx) {
            const int yy = y + dy - 1, xs = x + dx - 1;
            const bool ok = (yy >= 0 && yy < H && xs >= 0 && xs < W);
            tv[dy][dx] = ok;
            nvalid += ok ? 1 : 0;
            const u64* q = ib + ((size_t)yy * W + xs) * W64;
#pragma unroll
            for (int k = 0; k < W64; ++k) win[dy][dx][k] = ok ? q[k] : 0ull;
        }
    const int basev = nvalid * 64 * W64;

    u32 obuf[OPW / 32];
    u32 cur = 0;
    for (int oc = 0; oc < OPW; ++oc) {
        const u64* wo = &wlds[oc * 9 * W64];
        int pop = 0;
#pragma unroll
        for (int dy = 0; dy < 3; ++dy)
#pragma unroll
            for (int dx = 0; dx < 3; ++dx) {
                int tp = 0;
#pragma unroll
                for (int k = 0; k < W64; ++k)
                    tp += (int)__popcll(win[dy][dx][k] ^ wo[(dy * 3 + dx) * W64 + k]);
                pop += tv[dy][dx] ? tp : 0;
            }
        const int v = basev - 2 * pop;
        const double t = fma(Alds[oc], (double)v, Blds[oc]);
        cur |= (u32)(t < 0.0) << (oc & 31);
        if ((oc & 31) == 31) { obuf[oc >> 5] = cur; cur = 0; }
    }
    u32* op = out_bits + ((size_t)img * H * W + (size_t)y * W + x) * (OTOT / 32) + (obase >> 5);
#pragma unroll
    for (int j = 0; j < OPW / 32; ++j) op[j] = obuf[j];
}

// ---------------------------------------------------------------------------
// bconv + 2x2 pool: lane = CONV pixel (3x3 window only); pool = int max via
// shfl_xor(1) then shfl_xor(W) — exact (same ints, A>0 monotonic). 16 writer
// lanes/wave. LAST -> f32 htanh h5 (NCHW); else bit-packed u32 store.
// ---------------------------------------------------------------------------
template<int H, int W, int W64, int OTOT, int OPW, int MINW, bool LAST>
__global__ __launch_bounds__(256, MINW) void bconv_ps(
        const u64* __restrict__ in_bits, const u64* __restrict__ wb,
        const double* __restrict__ A, const double* __restrict__ B,
        u32* __restrict__ out_bits, float* __restrict__ h5) {
    const int tid = threadIdx.x;
    const int wave = tid >> 6, lane = tid & 63;
    constexpr int RPW = 64 / W;          // conv rows per wave
    constexpr int WPI = (H * W) / 64;    // waves per image
    constexpr int IPB = (WPI >= 4) ? 1 : 4 / WPI;
    const int img = (IPB == 1) ? blockIdx.z : blockIdx.z * IPB + wave;
    const int wii = (IPB == 1) ? blockIdx.y * 4 + wave : 0;
    const int y = wii * RPW + lane / W;
    const int x = lane % W;
    const int obase = blockIdx.x * OPW;
    constexpr int Hp = H / 2, Wp = W / 2;

    __shared__ u64 wlds[OPW * 9 * W64];
    __shared__ double Alds[OPW], Blds[OPW];
    {
        const u64* wg = wb + (size_t)obase * 9 * W64;
        for (int e = tid; e < OPW * 9 * W64; e += 256) wlds[e] = wg[e];
        for (int e = tid; e < OPW; e += 256) { Alds[e] = A[obase + e]; Blds[e] = B[obase + e]; }
    }
    __syncthreads();

    const u64* ib = in_bits + (size_t)img * H * W * W64;
    u64 win[3][3][W64];
    bool tv[3][3];
    int nvalid = 0;
#pragma unroll
    for (int dy = 0; dy < 3; ++dy)
#pragma unroll
        for (int dx = 0; dx < 3; ++dx) {
            const int yy = y + dy - 1, xs = x + dx - 1;
            const bool ok = (yy >= 0 && yy < H && xs >= 0 && xs < W);
            tv[dy][dx] = ok;
            nvalid += ok ? 1 : 0;
            const u64* q = ib + ((size_t)yy * W + xs) * W64;
#pragma unroll
            for (int k = 0; k < W64; ++k) win[dy][dx][k] = ok ? q[k] : 0ull;
        }
    const int basev = nvalid * 64 * W64;
    const bool writer = ((lane & 1) == 0) && ((lane & W) == 0);
    const int py = y >> 1, px = x >> 1;

    u32 obuf[OPW / 32];
    u32 cur = 0;
    for (int oc = 0; oc < OPW; ++oc) {
        const u64* wo = &wlds[oc * 9 * W64];
        int pop = 0;
#pragma unroll
        for (int dy = 0; dy < 3; ++dy)
#pragma unroll
            for (int dx = 0; dx < 3; ++dx) {
                int tp = 0;
#pragma unroll
                for (int k = 0; k < W64; ++k)
                    tp += (int)__popcll(win[dy][dx][k] ^ wo[(dy * 3 + dx) * W64 + k]);
                pop += tv[dy][dx] ? tp : 0;
            }
        const int v = basev - 2 * pop;
        int v2 = max(v, __shfl_xor(v, 1, 64));
        int v4 = max(v2, __shfl_xor(v2, W, 64));
        if (LAST) {
            const double t = fma(Alds[oc], (double)v4, Blds[oc]);
            const double hcl = fmin(1.0, fmax(-1.0, t));
            if (writer)
                h5[(((size_t)img * OTOT + obase + oc) * Hp + py) * Wp + px] = (float)hcl;
        } else {
            const double t = fma(Alds[oc], (double)v4, Blds[oc]);
            cur |= (u32)(t < 0.0) << (oc & 31);
            if ((oc & 31) == 31) { obuf[oc >> 5] = cur; cur = 0; }
        }
    }
    if (!LAST && writer) {
        u32* op = out_bits + ((size_t)img * Hp * Wp + (size_t)py * Wp + px) * (OTOT / 32) + (obase >> 5);
#pragma unroll
        for (int j = 0; j < OPW / 32; ++j) op[j] = obuf[j];
    }
}

// ---------------------------------------------------------------------------
// FC (f64 accumulate): out[n,10] = h5[n,8192] @ fcw^T + fcb
// ---------------------------------------------------------------------------
__global__ void fc_kernel(const float* __restrict__ h, const float* __restrict__ fcw,
                          const float* __restrict__ fcb, float* __restrict__ out) {
    const int n = blockIdx.x, t = threadIdx.x;
    double acc[10];
#pragma unroll
    for (int j = 0; j < 10; ++j) acc[j] = 0.0;
    const float* hn = h + (size_t)n * 8192;
    for (int k = t; k < 8192; k += 256) {
        double xv = (double)hn[k];
#pragma unroll
        for (int j = 0; j < 10; ++j) acc[j] += xv * (double)fcw[j * 8192 + k];
    }
    __shared__ double red[10][256];
#pragma unroll
    for (int j = 0; j < 10; ++j) red[j][t] = acc[j];
    __syncthreads();
    for (int r = 128; r > 0; r >>= 1) {
        if (t < r) {
#pragma unroll
            for (int j = 0; j < 10; ++j) red[j][t] += red[j][t + r];
        }
        __syncthreads();
    }
    if (t < 10) out[n * 10 + t] = (float)(red[t][0] + (double)fcb[t]);
}

// ===========================================================================
extern "C" void kernel_launch(void* const* d_in, const int* in_sizes, int n_in,
                              void* d_out, int out_size, void* d_ws, size_t ws_size,
                              hipStream_t stream) {
    const float* X = (const float*)d_in[0];
    BnArgs bn;
    PackArgs pk;
    const float* Wt0 = (const float*)d_in[1];
    for (int i = 0; i < 6; ++i) {
        bn.g[i] = (const float*)d_in[2 + 5 * i];
        bn.b[i] = (const float*)d_in[3 + 5 * i];
        bn.m[i] = (const float*)d_in[4 + 5 * i];
        bn.v[i] = (const float*)d_in[5 + 5 * i];
    }
    for (int i = 0; i < 5; ++i) pk.w[i] = (const float*)d_in[1 + 5 * (i + 1)];
    const float* fcw = (const float*)d_in[31];
    const float* fcb = (const float*)d_in[32];
    float* out = (float*)d_out;

    char* ws = (char*)d_ws;
    size_t off = 0;
    auto alloc = [&](size_t bytes) -> void* {
        void* p = ws + off;
        off = (off + bytes + 255) & ~(size_t)255;
        return p;
    };

    // ---- workspace ----
    double* scale_all = (double*)alloc(1792 * sizeof(double));
    double* shift_all = (double*)alloc(1792 * sizeof(double));
    double* A_all     = (double*)alloc(1664 * sizeof(double));
    const size_t WBN[5] = {128ull * 9 * 2, 256ull * 9 * 2, 256ull * 9 * 4,
                           512ull * 9 * 4, 512ull * 9 * 8};
    for (int i = 0; i < 5; ++i) pk.wb[i] = (u64*)alloc(WBN[i] * sizeof(u64));
    u64* bits0 = (u64*)alloc(256ull * 32 * 32 * 2 * sizeof(u64));
    u64* bits1 = (u64*)alloc(256ull * 16 * 16 * 2 * sizeof(u64));
    u64* bits2 = (u64*)alloc(256ull * 16 * 16 * 4 * sizeof(u64));
    u64* bits3 = (u64*)alloc(256ull * 8 * 8 * 4 * sizeof(u64));
    u64* bits4 = (u64*)alloc(256ull * 8 * 8 * 8 * sizeof(u64));
    float* h5  = (float*)alloc(256ull * 8192 * sizeof(float));

    if (off > ws_size) {
        zero_out<<<dim3((out_size + 255) / 256), dim3(256), 0, stream>>>(out, out_size);
        return;
    }

    const int BOF[6] = {0, 128, 256, 512, 768, 1280};
    const int AOF[5] = {0, 128, 384, 640, 1152};

    // ---- preps ----
    bn_prep_all<<<dim3(7), dim3(256), 0, stream>>>(bn, scale_all, shift_all);
    pack_all<<<dim3(1664), dim3(256), 0, stream>>>(pk, scale_all, A_all);

    // ---- conv0 ----
    conv0_pack<<<dim3(4, 256), dim3(256), 0, stream>>>(
        X, Wt0, scale_all + BOF[0], shift_all + BOF[0], bits0);

    // ---- binconv chain ----
    // L1: 128->128, 32x32 pool; conv-pixel lanes, OPW=64 -> grid (2,4,256)=2048
    bconv_ps<32, 32, 2, 128, 64, 4, false><<<dim3(2, 4, 256), dim3(256), 0, stream>>>(
        bits0, pk.wb[0], A_all + AOF[0], shift_all + BOF[1], (u32*)bits1, nullptr);
    // L2: 128->256, 16x16; OPW=64 -> grid (4,256)=1024
    bconv_np<16, 16, 2, 256, 64, 4><<<dim3(4, 256), dim3(256), 0, stream>>>(
        bits1, pk.wb[1], A_all + AOF[1], shift_all + BOF[2], (u32*)bits2);
    // L3: 256->256, 16x16 pool; conv-pixel lanes, OPW=32 -> grid (8,1,256)=2048
    bconv_ps<16, 16, 4, 256, 32, 3, false><<<dim3(8, 1, 256), dim3(256), 0, stream>>>(
        bits2, pk.wb[2], A_all + AOF[2], shift_all + BOF[3], (u32*)bits3, nullptr);
    // L4: 256->512, 8x8; OPW=32 -> grid (16,64)=1024
    bconv_np<8, 8, 4, 512, 32, 3><<<dim3(16, 64), dim3(256), 0, stream>>>(
        bits3, pk.wb[3], A_all + AOF[3], shift_all + BOF[4], (u32*)bits4);
    // L5: 512->512, 8x8 pool -> h5 f32; OPW=32, MINW=2 -> grid (16,1,64)=1024
    bconv_ps<8, 8, 8, 512, 32, 2, true><<<dim3(16, 1, 64), dim3(256), 0, stream>>>(
        bits4, pk.wb[4], A_all + AOF[4], shift_all + BOF[5], nullptr, h5);

    // ---- FC ----
    fc_kernel<<<dim3(256), dim3(256), 0, stream>>>(h5, fcw, fcb, out);
}

// Round 10
// 606.303 us; speedup vs baseline: 61.4278x; 1.0037x over previous
//
#include <hip/hip_runtime.h>
#include <cstdint>

#define EPS 1e-5
typedef unsigned long long u64;
typedef unsigned int u32;

// Pin a value into a VGPR: opaque to the compiler, cannot be rematerialized
// by re-loading from memory. Forces window residency across the oc loop.
#define PIN64(x) asm volatile("" : "+v"(x))

struct BnArgs { const float *g[6], *b[6], *m[6], *v[6]; };
struct PackArgs { const float* w[5]; u64* wb[5]; };

// ---------------------------------------------------------------------------
// Fused BN prep: offsets {0,128,256,512,768,1280}, total 1792.
// ---------------------------------------------------------------------------
__global__ void bn_prep_all(BnArgs p, double* __restrict__ scale_all,
                            double* __restrict__ shift_all) {
    int i = blockIdx.x * 256 + threadIdx.x;
    if (i >= 1792) return;
    int l, base;
    if (i < 128)       { l = 0; base = 0; }
    else if (i < 256)  { l = 1; base = 128; }
    else if (i < 512)  { l = 2; base = 256; }
    else if (i < 768)  { l = 3; base = 512; }
    else if (i < 1280) { l = 4; base = 768; }
    else               { l = 5; base = 1280; }
    const int c = i - base;
    double inv = (double)p.g[l][c] / sqrt((double)p.v[l][c] + EPS);
    scale_all[i] = inv;
    shift_all[i] = (double)p.b[l][c] - (double)p.m[l][c] * inv;
}

__global__ void zero_out(float* __restrict__ out, int n) {
    int i = blockIdx.x * blockDim.x + threadIdx.x;
    if (i < n) out[i] = 0.f;
}

// ---------------------------------------------------------------------------
// Fused weight pack for all 5 binconv layers; A = alpha*scale fused.
// ---------------------------------------------------------------------------
__global__ void pack_all(PackArgs pk, const double* __restrict__ scale_all,
                         double* __restrict__ A_all) {
    const int ob = blockIdx.x;
    const int t = threadIdx.x;
    int l, base, Cin, bnoff;
    if (ob < 128)       { l = 0; base = 0;    Cin = 128; bnoff = 128; }
    else if (ob < 384)  { l = 1; base = 128;  Cin = 128; bnoff = 256; }
    else if (ob < 640)  { l = 2; base = 384;  Cin = 256; bnoff = 512; }
    else if (ob < 1152) { l = 3; base = 640;  Cin = 256; bnoff = 768; }
    else                { l = 4; base = 1152; Cin = 512; bnoff = 1280; }
    const int o = ob - base;
    const float* wo = pk.w[l] + (size_t)o * Cin * 9;

    double s = 0.0;
    for (int k = t; k < Cin * 9; k += 256) s += fabs((double)wo[k]);
    __shared__ double red[256];
    red[t] = s;
    __syncthreads();
    for (int r = 128; r > 0; r >>= 1) {
        if (t < r) red[t] += red[t + r];
        __syncthreads();
    }
    if (t == 0) {
        double alpha = red[0] / (double)(Cin * 9);
        A_all[ob] = alpha * scale_all[bnoff + o];
    }

    const int W64 = Cin / 64;
    u64* wb = pk.wb[l];
    for (int e = t; e < 9 * W64; e += 256) {
        int tap = e / W64, word = e % W64;
        u64 bits = 0;
        for (int j = 0; j < 64; ++j) {
            int c = word * 64 + j;
            if (wo[c * 9 + tap] < 0.f) bits |= (1ull << j);
        }
        wb[((size_t)o * 9 + tap) * W64 + word] = bits;
    }
}

// ---------------------------------------------------------------------------
// conv0 (f64 exact), lane = pixel; filters+BN in LDS; in-lane bit packing.
// ---------------------------------------------------------------------------
__global__ __launch_bounds__(256) void conv0_pack(
        const float* __restrict__ x, const float* __restrict__ w0,
        const double* __restrict__ scale, const double* __restrict__ shift,
        u64* __restrict__ bits0) {
    __shared__ double wlds[128 * 27];
    __shared__ double sc[128], sh[128];
    const int tid = threadIdx.x;
    for (int e = tid; e < 128 * 27; e += 256) wlds[e] = (double)w0[e];
    for (int e = tid; e < 128; e += 256) { sc[e] = scale[e]; sh[e] = shift[e]; }
    __syncthreads();

    const int n = blockIdx.y;
    const int p = blockIdx.x * 256 + tid;
    const int y = p >> 5, xx = p & 31;
    const float* xn = x + (size_t)n * 3 * 32 * 32;

    double win[27];
#pragma unroll
    for (int c = 0; c < 3; ++c)
#pragma unroll
        for (int dy = 0; dy < 3; ++dy)
#pragma unroll
            for (int dx = 0; dx < 3; ++dx) {
                const int yy = y + dy - 1, xs = xx + dx - 1;
                const bool ok = (yy >= 0 && yy < 32 && xs >= 0 && xs < 32);
                win[(c * 3 + dy) * 3 + dx] = ok ? (double)xn[(c * 32 + yy) * 32 + xs] : 0.0;
            }

    u64* op = bits0 + ((size_t)n * 1024 + p) * 2;
#pragma unroll
    for (int og = 0; og < 2; ++og) {
        u64 word = 0;
#pragma unroll 2
        for (int j = 0; j < 64; ++j) {
            const int o = og * 64 + j;
            const double* wo = &wlds[o * 27];
            double acc = 0.0;
#pragma unroll
            for (int k = 0; k < 27; ++k) acc = fma(wo[k], win[k], acc);
            const double val = acc * sc[o] + sh[o];
            word |= (u64)(val < 0.0) << j;
        }
        op[og] = word;
    }
}

// ---------------------------------------------------------------------------
// bconv, no pool: lane = output pixel; 3x3 window PINNED in VGPRs; weights in
// LDS. MINW = min waves/EU (VGPR cap).
// ---------------------------------------------------------------------------
template<int H, int W, int W64, int OTOT, int OPW, int MINW>
__global__ __launch_bounds__(256, MINW) void bconv_np(
        const u64* __restrict__ in_bits, const u64* __restrict__ wb,
        const double* __restrict__ A, const double* __restrict__ B,
        u32* __restrict__ out_bits) {
    const int tid = threadIdx.x;
    const int wave = tid >> 6, lane = tid & 63;
    constexpr int WPI = (H * W) / 64;
    constexpr int IPB = (WPI >= 4) ? 1 : 4 / WPI;
    const int img = (IPB == 1) ? blockIdx.y : blockIdx.y * IPB + wave;
    const int pw  = (IPB == 1) ? wave : 0;
    const int p = pw * 64 + lane;
    const int y = p / W, x = p % W;
    const int obase = blockIdx.x * OPW;

    __shared__ u64 wlds[OPW * 9 * W64];
    __shared__ double Alds[OPW], Blds[OPW];
    {
        const u64* wg = wb + (size_t)obase * 9 * W64;
        for (int e = tid; e < OPW * 9 * W64; e += 256) wlds[e] = wg[e];
        for (int e = tid; e < OPW; e += 256) { Alds[e] = A[obase + e]; Blds[e] = B[obase + e]; }
    }
    __syncthreads();

    const u64* ib = in_bits + (size_t)img * H * W * W64;
    u64 win[3][3][W64];
    bool tv[3][3];
    int nvalid = 0;
#pragma unroll
    for (int dy = 0; dy < 3; ++dy)
#pragma unroll
        for (int dx = 0; dx < 3; ++dx) {
            const int yy = y + dy - 1, xs = x + dx - 1;
            const bool ok = (yy >= 0 && yy < H && xs >= 0 && xs < W);
            tv[dy][dx] = ok;
            nvalid += ok ? 1 : 0;
            const u64* q = ib + ((size_t)yy * W + xs) * W64;
#pragma unroll
            for (int k = 0; k < W64; ++k) win[dy][dx][k] = ok ? q[k] : 0ull;
        }
#pragma unroll
    for (int dy = 0; dy < 3; ++dy)
#pragma unroll
        for (int dx = 0; dx < 3; ++dx)
#pragma unroll
            for (int k = 0; k < W64; ++k) PIN64(win[dy][dx][k]);
    const int basev = nvalid * 64 * W64;

    u32 obuf[OPW / 32];
    u32 cur = 0;
    for (int oc = 0; oc < OPW; ++oc) {
        const u64* wo = &wlds[oc * 9 * W64];
        int pop = 0;
#pragma unroll
        for (int dy = 0; dy < 3; ++dy)
#pragma unroll
            for (int dx = 0; dx < 3; ++dx) {
                int tp = 0;
#pragma unroll
                for (int k = 0; k < W64; ++k)
                    tp += (int)__popcll(win[dy][dx][k] ^ wo[(dy * 3 + dx) * W64 + k]);
                pop += tv[dy][dx] ? tp : 0;
            }
        const int v = basev - 2 * pop;
        const double t = fma(Alds[oc], (double)v, Blds[oc]);
        cur |= (u32)(t < 0.0) << (oc & 31);
        if ((oc & 31) == 31) { obuf[oc >> 5] = cur; cur = 0; }
    }
    u32* op = out_bits + ((size_t)img * H * W + (size_t)y * W + x) * (OTOT / 32) + (obase >> 5);
#pragma unroll
    for (int j = 0; j < OPW / 32; ++j) op[j] = obuf[j];
}

// ---------------------------------------------------------------------------
// bconv + 2x2 pool: lane = CONV pixel; window PINNED; pool = int max via
// shfl_xor(1), shfl_xor(W) — exact. LAST -> f32 htanh h5 (NCHW).
// ---------------------------------------------------------------------------
template<int H, int W, int W64, int OTOT, int OPW, int MINW, bool LAST>
__global__ __launch_bounds__(256, MINW) void bconv_ps(
        const u64* __restrict__ in_bits, const u64* __restrict__ wb,
        const double* __restrict__ A, const double* __restrict__ B,
        u32* __restrict__ out_bits, float* __restrict__ h5) {
    const int tid = threadIdx.x;
    const int wave = tid >> 6, lane = tid & 63;
    constexpr int RPW = 64 / W;
    constexpr int WPI = (H * W) / 64;
    constexpr int IPB = (WPI >= 4) ? 1 : 4 / WPI;
    const int img = (IPB == 1) ? blockIdx.z : blockIdx.z * IPB + wave;
    const int wii = (IPB == 1) ? blockIdx.y * 4 + wave : 0;
    const int y = wii * RPW + lane / W;
    const int x = lane % W;
    const int obase = blockIdx.x * OPW;
    constexpr int Hp = H / 2, Wp = W / 2;

    __shared__ u64 wlds[OPW * 9 * W64];
    __shared__ double Alds[OPW], Blds[OPW];
    {
        const u64* wg = wb + (size_t)obase * 9 * W64;
        for (int e = tid; e < OPW * 9 * W64; e += 256) wlds[e] = wg[e];
        for (int e = tid; e < OPW; e += 256) { Alds[e] = A[obase + e]; Blds[e] = B[obase + e]; }
    }
    __syncthreads();

    const u64* ib = in_bits + (size_t)img * H * W * W64;
    u64 win[3][3][W64];
    bool tv[3][3];
    int nvalid = 0;
#pragma unroll
    for (int dy = 0; dy < 3; ++dy)
#pragma unroll
        for (int dx = 0; dx < 3; ++dx) {
            const int yy = y + dy - 1, xs = x + dx - 1;
            const bool ok = (yy >= 0 && yy < H && xs >= 0 && xs < W);
            tv[dy][dx] = ok;
            nvalid += ok ? 1 : 0;
            const u64* q = ib + ((size_t)yy * W + xs) * W64;
#pragma unroll
            for (int k = 0; k < W64; ++k) win[dy][dx][k] = ok ? q[k] : 0ull;
        }
#pragma unroll
    for (int dy = 0; dy < 3; ++dy)
#pragma unroll
        for (int dx = 0; dx < 3; ++dx)
#pragma unroll
            for (int k = 0; k < W64; ++k) PIN64(win[dy][dx][k]);
    const int basev = nvalid * 64 * W64;
    const bool writer = ((lane & 1) == 0) && ((lane & W) == 0);
    const int py = y >> 1, px = x >> 1;

    u32 obuf[OPW / 32];
    u32 cur = 0;
    for (int oc = 0; oc < OPW; ++oc) {
        const u64* wo = &wlds[oc * 9 * W64];
        int pop = 0;
#pragma unroll
        for (int dy = 0; dy < 3; ++dy)
#pragma unroll
            for (int dx = 0; dx < 3; ++dx) {
                int tp = 0;
#pragma unroll
                for (int k = 0; k < W64; ++k)
                    tp += (int)__popcll(win[dy][dx][k] ^ wo[(dy * 3 + dx) * W64 + k]);
                pop += tv[dy][dx] ? tp : 0;
            }
        const int v = basev - 2 * pop;
        int v2 = max(v, __shfl_xor(v, 1, 64));
        int v4 = max(v2, __shfl_xor(v2, W, 64));
        if (LAST) {
            const double t = fma(Alds[oc], (double)v4, Blds[oc]);
            const double hcl = fmin(1.0, fmax(-1.0, t));
            if (writer)
                h5[(((size_t)img * OTOT + obase + oc) * Hp + py) * Wp + px] = (float)hcl;
        } else {
            const double t = fma(Alds[oc], (double)v4, Blds[oc]);
            cur |= (u32)(t < 0.0) << (oc & 31);
            if ((oc & 31) == 31) { obuf[oc >> 5] = cur; cur = 0; }
        }
    }
    if (!LAST && writer) {
        u32* op = out_bits + ((size_t)img * Hp * Wp + (size_t)py * Wp + px) * (OTOT / 32) + (obase >> 5);
#pragma unroll
        for (int j = 0; j < OPW / 32; ++j) op[j] = obuf[j];
    }
}

// ---------------------------------------------------------------------------
// FC (f64 accumulate): out[n,10] = h5[n,8192] @ fcw^T + fcb
// ---------------------------------------------------------------------------
__global__ void fc_kernel(const float* __restrict__ h, const float* __restrict__ fcw,
                          const float* __restrict__ fcb, float* __restrict__ out) {
    const int n = blockIdx.x, t = threadIdx.x;
    double acc[10];
#pragma unroll
    for (int j = 0; j < 10; ++j) acc[j] = 0.0;
    const float* hn = h + (size_t)n * 8192;
    for (int k = t; k < 8192; k += 256) {
        double xv = (double)hn[k];
#pragma unroll
        for (int j = 0; j < 10; ++j) acc[j] += xv * (double)fcw[j * 8192 + k];
    }
    __shared__ double red[10][256];
#pragma unroll
    for (int j = 0; j < 10; ++j) red[j][t] = acc[j];
    __syncthreads();
    for (int r = 128; r > 0; r >>= 1) {
        if (t < r) {
#pragma unroll
            for (int j = 0; j < 10; ++j) red[j][t] += red[j][t + r];
        }
        __syncthreads();
    }
    if (t < 10) out[n * 10 + t] = (float)(red[t][0] + (double)fcb[t]);
}

// ===========================================================================
extern "C" void kernel_launch(void* const* d_in, const int* in_sizes, int n_in,
                              void* d_out, int out_size, void* d_ws, size_t ws_size,
                              hipStream_t stream) {
    const float* X = (const float*)d_in[0];
    BnArgs bn;
    PackArgs pk;
    const float* Wt0 = (const float*)d_in[1];
    for (int i = 0; i < 6; ++i) {
        bn.g[i] = (const float*)d_in[2 + 5 * i];
        bn.b[i] = (const float*)d_in[3 + 5 * i];
        bn.m[i] = (const float*)d_in[4 + 5 * i];
        bn.v[i] = (const float*)d_in[5 + 5 * i];
    }
    for (int i = 0; i < 5; ++i) pk.w[i] = (const float*)d_in[1 + 5 * (i + 1)];
    const float* fcw = (const float*)d_in[31];
    const float* fcb = (const float*)d_in[32];
    float* out = (float*)d_out;

    char* ws = (char*)d_ws;
    size_t off = 0;
    auto alloc = [&](size_t bytes) -> void* {
        void* p = ws + off;
        off = (off + bytes + 255) & ~(size_t)255;
        return p;
    };

    // ---- workspace ----
    double* scale_all = (double*)alloc(1792 * sizeof(double));
    double* shift_all = (double*)alloc(1792 * sizeof(double));
    double* A_all     = (double*)alloc(1664 * sizeof(double));
    const size_t WBN[5] = {128ull * 9 * 2, 256ull * 9 * 2, 256ull * 9 * 4,
                           512ull * 9 * 4, 512ull * 9 * 8};
    for (int i = 0; i < 5; ++i) pk.wb[i] = (u64*)alloc(WBN[i] * sizeof(u64));
    u64* bits0 = (u64*)alloc(256ull * 32 * 32 * 2 * sizeof(u64));
    u64* bits1 = (u64*)alloc(256ull * 16 * 16 * 2 * sizeof(u64));
    u64* bits2 = (u64*)alloc(256ull * 16 * 16 * 4 * sizeof(u64));
    u64* bits3 = (u64*)alloc(256ull * 8 * 8 * 4 * sizeof(u64));
    u64* bits4 = (u64*)alloc(256ull * 8 * 8 * 8 * sizeof(u64));
    float* h5  = (float*)alloc(256ull * 8192 * sizeof(float));

    if (off > ws_size) {
        zero_out<<<dim3((out_size + 255) / 256), dim3(256), 0, stream>>>(out, out_size);
        return;
    }

    const int BOF[6] = {0, 128, 256, 512, 768, 1280};
    const int AOF[5] = {0, 128, 384, 640, 1152};

    // ---- preps ----
    bn_prep_all<<<dim3(7), dim3(256), 0, stream>>>(bn, scale_all, shift_all);
    pack_all<<<dim3(1664), dim3(256), 0, stream>>>(pk, scale_all, A_all);

    // ---- conv0 ----
    conv0_pack<<<dim3(4, 256), dim3(256), 0, stream>>>(
        X, Wt0, scale_all + BOF[0], shift_all + BOF[0], bits0);

    // ---- binconv chain ----
    // L1: 128->128, 32x32 pool; conv-pixel lanes, OPW=64 -> 2048 blocks
    bconv_ps<32, 32, 2, 128, 64, 4, false><<<dim3(2, 4, 256), dim3(256), 0, stream>>>(
        bits0, pk.wb[0], A_all + AOF[0], shift_all + BOF[1], (u32*)bits1, nullptr);
    // L2: 128->256, 16x16; OPW=64 -> 1024 blocks
    bconv_np<16, 16, 2, 256, 64, 4><<<dim3(4, 256), dim3(256), 0, stream>>>(
        bits1, pk.wb[1], A_all + AOF[1], shift_all + BOF[2], (u32*)bits2);
    // L3: 256->256, 16x16 pool; conv-pixel lanes, OPW=32 -> 2048 blocks
    bconv_ps<16, 16, 4, 256, 32, 3, false><<<dim3(8, 1, 256), dim3(256), 0, stream>>>(
        bits2, pk.wb[2], A_all + AOF[2], shift_all + BOF[3], (u32*)bits3, nullptr);
    // L4: 256->512, 8x8; OPW=32 -> 1024 blocks
    bconv_np<8, 8, 4, 512, 32, 3><<<dim3(16, 64), dim3(256), 0, stream>>>(
        bits3, pk.wb[3], A_all + AOF[3], shift_all + BOF[4], (u32*)bits4);
    // L5: 512->512, 8x8 pool -> h5 f32; OPW=32, MINW=2 -> 1024 blocks
    bconv_ps<8, 8, 8, 512, 32, 2, true><<<dim3(16, 1, 64), dim3(256), 0, stream>>>(
        bits4, pk.wb[4], A_all + AOF[4], shift_all + BOF[5], nullptr, h5);

    // ---- FC ----
    fc_kernel<<<dim3(256), dim3(256), 0, stream>>>(h5, fcw, fcb, out);
}

// Round 11
// 593.635 us; speedup vs baseline: 62.7386x; 1.0213x over previous
//
#include <hip/hip_runtime.h>
#include <cstdint>

#define EPS 1e-5
typedef unsigned long long u64;
typedef unsigned int u32;

struct BnArgs { const float *g[6], *b[6], *m[6], *v[6]; };
struct PackArgs { const float* w[5]; u64* wbt[5]; };

// ---------------------------------------------------------------------------
// Fused BN prep: offsets {0,128,256,512,768,1280}, total 1792.
// ---------------------------------------------------------------------------
__global__ void bn_prep_all(BnArgs p, double* __restrict__ scale_all,
                            double* __restrict__ shift_all) {
    int i = blockIdx.x * 256 + threadIdx.x;
    if (i >= 1792) return;
    int l, base;
    if (i < 128)       { l = 0; base = 0; }
    else if (i < 256)  { l = 1; base = 128; }
    else if (i < 512)  { l = 2; base = 256; }
    else if (i < 768)  { l = 3; base = 512; }
    else if (i < 1280) { l = 4; base = 768; }
    else               { l = 5; base = 1280; }
    const int c = i - base;
    double inv = (double)p.g[l][c] / sqrt((double)p.v[l][c] + EPS);
    scale_all[i] = inv;
    shift_all[i] = (double)p.b[l][c] - (double)p.m[l][c] * inv;
}

__global__ void zero_out(float* __restrict__ out, int n) {
    int i = blockIdx.x * blockDim.x + threadIdx.x;
    if (i < n) out[i] = 0.f;
}

// ---------------------------------------------------------------------------
// Fused weight pack, TRANSPOSED tap-major layout: wbt[(tap*OTOT + o)*W64 + w]
// bit j of word w = (weight[o][w*64+j][tap] < 0). A = alpha*scale fused.
// ---------------------------------------------------------------------------
__global__ void pack_all(PackArgs pk, const double* __restrict__ scale_all,
                         double* __restrict__ A_all) {
    const int ob = blockIdx.x;
    const int t = threadIdx.x;
    int l, base, Cin, bnoff, OTOT;
    if (ob < 128)       { l = 0; base = 0;    Cin = 128; bnoff = 128;  OTOT = 128; }
    else if (ob < 384)  { l = 1; base = 128;  Cin = 128; bnoff = 256;  OTOT = 256; }
    else if (ob < 640)  { l = 2; base = 384;  Cin = 256; bnoff = 512;  OTOT = 256; }
    else if (ob < 1152) { l = 3; base = 640;  Cin = 256; bnoff = 768;  OTOT = 512; }
    else                { l = 4; base = 1152; Cin = 512; bnoff = 1280; OTOT = 512; }
    const int o = ob - base;
    const float* wo = pk.w[l] + (size_t)o * Cin * 9;

    double s = 0.0;
    for (int k = t; k < Cin * 9; k += 256) s += fabs((double)wo[k]);
    __shared__ double red[256];
    red[t] = s;
    __syncthreads();
    for (int r = 128; r > 0; r >>= 1) {
        if (t < r) red[t] += red[t + r];
        __syncthreads();
    }
    if (t == 0) {
        double alpha = red[0] / (double)(Cin * 9);
        A_all[ob] = alpha * scale_all[bnoff + o];
    }

    const int W64 = Cin / 64;
    u64* wbt = pk.wbt[l];
    for (int e = t; e < 9 * W64; e += 256) {
        int tap = e / W64, word = e % W64;
        u64 bits = 0;
        for (int j = 0; j < 64; ++j) {
            int c = word * 64 + j;
            if (wo[c * 9 + tap] < 0.f) bits |= (1ull << j);
        }
        wbt[((size_t)tap * OTOT + o) * W64 + word] = bits;
    }
}

// ---------------------------------------------------------------------------
// conv0 (f64 exact), lane = pixel; filters+BN in LDS; in-lane bit packing.
// ---------------------------------------------------------------------------
__global__ __launch_bounds__(256) void conv0_pack(
        const float* __restrict__ x, const float* __restrict__ w0,
        const double* __restrict__ scale, const double* __restrict__ shift,
        u64* __restrict__ bits0) {
    __shared__ double wlds[128 * 27];
    __shared__ double sc[128], sh[128];
    const int tid = threadIdx.x;
    for (int e = tid; e < 128 * 27; e += 256) wlds[e] = (double)w0[e];
    for (int e = tid; e < 128; e += 256) { sc[e] = scale[e]; sh[e] = shift[e]; }
    __syncthreads();

    const int n = blockIdx.y;
    const int p = blockIdx.x * 256 + tid;
    const int y = p >> 5, xx = p & 31;
    const float* xn = x + (size_t)n * 3 * 32 * 32;

    double win[27];
#pragma unroll
    for (int c = 0; c < 3; ++c)
#pragma unroll
        for (int dy = 0; dy < 3; ++dy)
#pragma unroll
            for (int dx = 0; dx < 3; ++dx) {
                const int yy = y + dy - 1, xs = xx + dx - 1;
                const bool ok = (yy >= 0 && yy < 32 && xs >= 0 && xs < 32);
                win[(c * 3 + dy) * 3 + dx] = ok ? (double)xn[(c * 32 + yy) * 32 + xs] : 0.0;
            }

    u64* op = bits0 + ((size_t)n * 1024 + p) * 2;
#pragma unroll
    for (int og = 0; og < 2; ++og) {
        u64 word = 0;
#pragma unroll 2
        for (int j = 0; j < 64; ++j) {
            const int o = og * 64 + j;
            const double* wo = &wlds[o * 27];
            double acc = 0.0;
#pragma unroll
            for (int k = 0; k < 27; ++k) acc = fma(wo[k], win[k], acc);
            const double val = acc * sc[o] + sh[o];
            word |= (u64)(val < 0.0) << j;
        }
        op[og] = word;
    }
}

// ---------------------------------------------------------------------------
// bconv3: taps-outer, oc-inner (32 int accumulators — cannot be sunk/spilled
// cheaply, forcing residency). lane = conv pixel. Weights are wave-uniform
// (tap-major layout) -> scalar s_load path, no LDS, no syncthreads.
// POOL: 2x2 int max via shfl_xor(1), shfl_xor(W) on exact sums.
// LAST: htanh f64 -> f32 h5 (NCHW). Else bit-pack u32 per 32-oc chunk.
// ---------------------------------------------------------------------------
template<int H, int W, int W64, int OTOT, bool POOL, bool LAST, int MINW>
__global__ __launch_bounds__(256, MINW) void bconv3(
        const u64* __restrict__ in_bits, const u64* __restrict__ wbt,
        const double* __restrict__ A, const double* __restrict__ B,
        u32* __restrict__ out_bits, float* __restrict__ h5) {
    const int tid = threadIdx.x;
    const int wave = tid >> 6, lane = tid & 63;
    constexpr int OPW = 32;
    constexpr int WPI = (H * W) / 64;            // waves per image
    constexpr int IPB = (WPI >= 4) ? 1 : (4 / WPI);
    const int img = (IPB == 1) ? blockIdx.z : blockIdx.z * IPB + wave;
    const int wii = (IPB == 1) ? (blockIdx.y * 4 + wave) : 0;
    const int y = wii * (64 / W) + lane / W;
    const int x = lane % W;
    const int obase = blockIdx.x * OPW;

    const u64* ib = in_bits + (size_t)img * H * W * W64;

    int acc[OPW];
#pragma unroll
    for (int i = 0; i < OPW; ++i) acc[i] = 0;
    int nvalid = 0;

#pragma unroll 1
    for (int dy = 0; dy < 3; ++dy) {
#pragma unroll 1
        for (int dx = 0; dx < 3; ++dx) {
            const int yy = y + dy - 1, xs = x + dx - 1;
            const bool ok = (yy >= 0 && yy < H && xs >= 0 && xs < W);
            nvalid += ok ? 1 : 0;
            u64 wn[W64];
            const u64* q = ib + ((size_t)yy * W + xs) * W64;
#pragma unroll
            for (int k = 0; k < W64; ++k) wn[k] = ok ? q[k] : 0ull;
            // wave-uniform weight base for this tap (scalar loads)
            const u64* wt = wbt + ((size_t)(dy * 3 + dx) * OTOT + obase) * W64;
#pragma unroll
            for (int oc = 0; oc < OPW; ++oc) {
                int tp = 0;
#pragma unroll
                for (int k = 0; k < W64; ++k)
                    tp += (int)__popcll(wn[k] ^ wt[oc * W64 + k]);
                acc[oc] += ok ? tp : 0;
            }
        }
    }

    const int basev = nvalid * 64 * W64;
    constexpr int Hp = POOL ? H / 2 : H, Wp = POOL ? W / 2 : W;
    const bool writer = (!POOL) || (((lane & 1) == 0) && ((lane & W) == 0));
    const int py = POOL ? (y >> 1) : y, px = POOL ? (x >> 1) : x;

    u32 cur = 0;
#pragma unroll
    for (int oc = 0; oc < OPW; ++oc) {
        int v = basev - 2 * acc[oc];
        if (POOL) {
            int v2 = max(v, __shfl_xor(v, 1, 64));
            v = max(v2, __shfl_xor(v2, W, 64));
        }
        const double t = fma(A[obase + oc], (double)v, B[obase + oc]);
        if (LAST) {
            const double hcl = fmin(1.0, fmax(-1.0, t));
            if (writer)
                h5[(((size_t)img * OTOT + obase + oc) * Hp + py) * Wp + px] = (float)hcl;
        } else {
            cur |= (u32)(t < 0.0) << oc;
        }
    }
    if (!LAST && writer) {
        out_bits[((size_t)img * Hp * Wp + (size_t)py * Wp + px) * (OTOT / 32) + (obase >> 5)] = cur;
    }
}

// ---------------------------------------------------------------------------
// FC (f64 accumulate): out[n,10] = h5[n,8192] @ fcw^T + fcb
// ---------------------------------------------------------------------------
__global__ void fc_kernel(const float* __restrict__ h, const float* __restrict__ fcw,
                          const float* __restrict__ fcb, float* __restrict__ out) {
    const int n = blockIdx.x, t = threadIdx.x;
    double acc[10];
#pragma unroll
    for (int j = 0; j < 10; ++j) acc[j] = 0.0;
    const float* hn = h + (size_t)n * 8192;
    for (int k = t; k < 8192; k += 256) {
        double xv = (double)hn[k];
#pragma unroll
        for (int j = 0; j < 10; ++j) acc[j] += xv * (double)fcw[j * 8192 + k];
    }
    __shared__ double red[10][256];
#pragma unroll
    for (int j = 0; j < 10; ++j) red[j][t] = acc[j];
    __syncthreads();
    for (int r = 128; r > 0; r >>= 1) {
        if (t < r) {
#pragma unroll
            for (int j = 0; j < 10; ++j) red[j][t] += red[j][t + r];
        }
        __syncthreads();
    }
    if (t < 10) out[n * 10 + t] = (float)(red[t][0] + (double)fcb[t]);
}

// ===========================================================================
extern "C" void kernel_launch(void* const* d_in, const int* in_sizes, int n_in,
                              void* d_out, int out_size, void* d_ws, size_t ws_size,
                              hipStream_t stream) {
    const float* X = (const float*)d_in[0];
    BnArgs bn;
    PackArgs pk;
    const float* Wt0 = (const float*)d_in[1];
    for (int i = 0; i < 6; ++i) {
        bn.g[i] = (const float*)d_in[2 + 5 * i];
        bn.b[i] = (const float*)d_in[3 + 5 * i];
        bn.m[i] = (const float*)d_in[4 + 5 * i];
        bn.v[i] = (const float*)d_in[5 + 5 * i];
    }
    for (int i = 0; i < 5; ++i) pk.w[i] = (const float*)d_in[1 + 5 * (i + 1)];
    const float* fcw = (const float*)d_in[31];
    const float* fcb = (const float*)d_in[32];
    float* out = (float*)d_out;

    char* ws = (char*)d_ws;
    size_t off = 0;
    auto alloc = [&](size_t bytes) -> void* {
        void* p = ws + off;
        off = (off + bytes + 255) & ~(size_t)255;
        return p;
    };

    // ---- workspace ----
    double* scale_all = (double*)alloc(1792 * sizeof(double));
    double* shift_all = (double*)alloc(1792 * sizeof(double));
    double* A_all     = (double*)alloc(1664 * sizeof(double));
    const size_t WBN[5] = {128ull * 9 * 2, 256ull * 9 * 2, 256ull * 9 * 4,
                           512ull * 9 * 4, 512ull * 9 * 8};
    for (int i = 0; i < 5; ++i) pk.wbt[i] = (u64*)alloc(WBN[i] * sizeof(u64));
    u64* bits0 = (u64*)alloc(256ull * 32 * 32 * 2 * sizeof(u64));
    u64* bits1 = (u64*)alloc(256ull * 16 * 16 * 2 * sizeof(u64));
    u64* bits2 = (u64*)alloc(256ull * 16 * 16 * 4 * sizeof(u64));
    u64* bits3 = (u64*)alloc(256ull * 8 * 8 * 4 * sizeof(u64));
    u64* bits4 = (u64*)alloc(256ull * 8 * 8 * 8 * sizeof(u64));
    float* h5  = (float*)alloc(256ull * 8192 * sizeof(float));

    if (off > ws_size) {
        zero_out<<<dim3((out_size + 255) / 256), dim3(256), 0, stream>>>(out, out_size);
        return;
    }

    const int BOF[6] = {0, 128, 256, 512, 768, 1280};
    const int AOF[5] = {0, 128, 384, 640, 1152};

    // ---- preps ----
    bn_prep_all<<<dim3(7), dim3(256), 0, stream>>>(bn, scale_all, shift_all);
    pack_all<<<dim3(1664), dim3(256), 0, stream>>>(pk, scale_all, A_all);

    // ---- conv0 ----
    conv0_pack<<<dim3(4, 256), dim3(256), 0, stream>>>(
        X, Wt0, scale_all + BOF[0], shift_all + BOF[0], bits0);

    // ---- binconv chain (taps-outer, 32-acc inner) ----
    // L1: 128->128, 32x32, pool
    bconv3<32, 32, 2, 128, true, false, 4><<<dim3(4, 4, 256), dim3(256), 0, stream>>>(
        bits0, pk.wbt[0], A_all + AOF[0], shift_all + BOF[1], (u32*)bits1, nullptr);
    // L2: 128->256, 16x16
    bconv3<16, 16, 2, 256, false, false, 4><<<dim3(8, 1, 256), dim3(256), 0, stream>>>(
        bits1, pk.wbt[1], A_all + AOF[1], shift_all + BOF[2], (u32*)bits2, nullptr);
    // L3: 256->256, 16x16, pool
    bconv3<16, 16, 4, 256, true, false, 4><<<dim3(8, 1, 256), dim3(256), 0, stream>>>(
        bits2, pk.wbt[2], A_all + AOF[2], shift_all + BOF[3], (u32*)bits3, nullptr);
    // L4: 256->512, 8x8
    bconv3<8, 8, 4, 512, false, false, 4><<<dim3(16, 1, 64), dim3(256), 0, stream>>>(
        bits3, pk.wbt[3], A_all + AOF[3], shift_all + BOF[4], (u32*)bits4, nullptr);
    // L5: 512->512, 8x8, pool -> h5
    bconv3<8, 8, 8, 512, true, true, 4><<<dim3(16, 1, 64), dim3(256), 0, stream>>>(
        bits4, pk.wbt[4], A_all + AOF[4], shift_all + BOF[5], nullptr, h5);

    // ---- FC ----
    fc_kernel<<<dim3(256), dim3(256), 0, stream>>>(h5, fcw, fcb, out);
}

// Round 12
// 588.369 us; speedup vs baseline: 63.3002x; 1.0090x over previous
//
#include <hip/hip_runtime.h>
#include <cstdint>

#define EPS 1e-5
typedef unsigned long long u64;
typedef unsigned int u32;

struct BnArgs { const float *g[6], *b[6], *m[6], *v[6]; };
struct PackArgs { const float* w[5]; u64* wbt[5]; };

// ---------------------------------------------------------------------------
// Fused BN prep: offsets {0,128,256,512,768,1280}, total 1792.
// ---------------------------------------------------------------------------
__global__ void bn_prep_all(BnArgs p, double* __restrict__ scale_all,
                            double* __restrict__ shift_all) {
    int i = blockIdx.x * 256 + threadIdx.x;
    if (i >= 1792) return;
    int l, base;
    if (i < 128)       { l = 0; base = 0; }
    else if (i < 256)  { l = 1; base = 128; }
    else if (i < 512)  { l = 2; base = 256; }
    else if (i < 768)  { l = 3; base = 512; }
    else if (i < 1280) { l = 4; base = 768; }
    else               { l = 5; base = 1280; }
    const int c = i - base;
    double inv = (double)p.g[l][c] / sqrt((double)p.v[l][c] + EPS);
    scale_all[i] = inv;
    shift_all[i] = (double)p.b[l][c] - (double)p.m[l][c] * inv;
}

__global__ void zero_out(float* __restrict__ out, int n) {
    int i = blockIdx.x * blockDim.x + threadIdx.x;
    if (i < n) out[i] = 0.f;
}

// ---------------------------------------------------------------------------
// Fused weight pack, tap-major layout: wbt[(tap*OTOT + o)*W64 + w].
// A = alpha*scale fused.
// ---------------------------------------------------------------------------
__global__ void pack_all(PackArgs pk, const double* __restrict__ scale_all,
                         double* __restrict__ A_all) {
    const int ob = blockIdx.x;
    const int t = threadIdx.x;
    int l, base, Cin, bnoff, OTOT;
    if (ob < 128)       { l = 0; base = 0;    Cin = 128; bnoff = 128;  OTOT = 128; }
    else if (ob < 384)  { l = 1; base = 128;  Cin = 128; bnoff = 256;  OTOT = 256; }
    else if (ob < 640)  { l = 2; base = 384;  Cin = 256; bnoff = 512;  OTOT = 256; }
    else if (ob < 1152) { l = 3; base = 640;  Cin = 256; bnoff = 768;  OTOT = 512; }
    else                { l = 4; base = 1152; Cin = 512; bnoff = 1280; OTOT = 512; }
    const int o = ob - base;
    const float* wo = pk.w[l] + (size_t)o * Cin * 9;

    double s = 0.0;
    for (int k = t; k < Cin * 9; k += 256) s += fabs((double)wo[k]);
    __shared__ double red[256];
    red[t] = s;
    __syncthreads();
    for (int r = 128; r > 0; r >>= 1) {
        if (t < r) red[t] += red[t + r];
        __syncthreads();
    }
    if (t == 0) {
        double alpha = red[0] / (double)(Cin * 9);
        A_all[ob] = alpha * scale_all[bnoff + o];
    }

    const int W64 = Cin / 64;
    u64* wbt = pk.wbt[l];
    for (int e = t; e < 9 * W64; e += 256) {
        int tap = e / W64, word = e % W64;
        u64 bits = 0;
        for (int j = 0; j < 64; ++j) {
            int c = word * 64 + j;
            if (wo[c * 9 + tap] < 0.f) bits |= (1ull << j);
        }
        wbt[((size_t)tap * OTOT + o) * W64 + word] = bits;
    }
}

// ---------------------------------------------------------------------------
// conv0 (f64 exact), lane = pixel; filters+BN in LDS; in-lane bit packing.
// ---------------------------------------------------------------------------
__global__ __launch_bounds__(256) void conv0_pack(
        const float* __restrict__ x, const float* __restrict__ w0,
        const double* __restrict__ scale, const double* __restrict__ shift,
        u64* __restrict__ bits0) {
    __shared__ double wlds[128 * 27];
    __shared__ double sc[128], sh[128];
    const int tid = threadIdx.x;
    for (int e = tid; e < 128 * 27; e += 256) wlds[e] = (double)w0[e];
    for (int e = tid; e < 128; e += 256) { sc[e] = scale[e]; sh[e] = shift[e]; }
    __syncthreads();

    const int n = blockIdx.y;
    const int p = blockIdx.x * 256 + tid;
    const int y = p >> 5, xx = p & 31;
    const float* xn = x + (size_t)n * 3 * 32 * 32;

    double win[27];
#pragma unroll
    for (int c = 0; c < 3; ++c)
#pragma unroll
        for (int dy = 0; dy < 3; ++dy)
#pragma unroll
            for (int dx = 0; dx < 3; ++dx) {
                const int yy = y + dy - 1, xs = xx + dx - 1;
                const bool ok = (yy >= 0 && yy < 32 && xs >= 0 && xs < 32);
                win[(c * 3 + dy) * 3 + dx] = ok ? (double)xn[(c * 32 + yy) * 32 + xs] : 0.0;
            }

    u64* op = bits0 + ((size_t)n * 1024 + p) * 2;
#pragma unroll
    for (int og = 0; og < 2; ++og) {
        u64 word = 0;
#pragma unroll 2
        for (int j = 0; j < 64; ++j) {
            const int o = og * 64 + j;
            const double* wo = &wlds[o * 27];
            double acc = 0.0;
#pragma unroll
            for (int k = 0; k < 27; ++k) acc = fma(wo[k], win[k], acc);
            const double val = acc * sc[o] + sh[o];
            word |= (u64)(val < 0.0) << j;
        }
        op[og] = word;
    }
}

// ---------------------------------------------------------------------------
// bconv4: taps-outer, oc-inner with 32 resident int accumulators; lane = conv
// pixel. Weights for this block's 32-oc chunk staged in LDS (broadcast
// ds_read in the tap loop — short latency, no residency pressure).
// POOL: 2x2 int max via shfl_xor(1), shfl_xor(W) on exact sums.
// LAST: htanh f64 -> f32 h5 (NCHW). Else bit-pack u32 per 32-oc chunk.
// ---------------------------------------------------------------------------
template<int H, int W, int W64, int OTOT, bool POOL, bool LAST, int MINW>
__global__ __launch_bounds__(256, MINW) void bconv4(
        const u64* __restrict__ in_bits, const u64* __restrict__ wbt,
        const double* __restrict__ A, const double* __restrict__ B,
        u32* __restrict__ out_bits, float* __restrict__ h5) {
    const int tid = threadIdx.x;
    const int wave = tid >> 6, lane = tid & 63;
    constexpr int OPW = 32;
    constexpr int WPI = (H * W) / 64;            // waves per image
    constexpr int IPB = (WPI >= 4) ? 1 : (4 / WPI);
    const int img = (IPB == 1) ? blockIdx.z : blockIdx.z * IPB + wave;
    const int wii = (IPB == 1) ? (blockIdx.y * 4 + wave) : 0;
    const int y = wii * (64 / W) + lane / W;
    const int x = lane % W;
    const int obase = blockIdx.x * OPW;

    // ---- stage this chunk's weights + consts into LDS ----
    __shared__ u64 wl[9 * OPW * W64];
    __shared__ double Ald[OPW], Bld[OPW];
    {
        for (int e = tid; e < 9 * OPW * W64; e += 256) {
            const int tap = e / (OPW * W64), r = e % (OPW * W64);
            wl[e] = wbt[((size_t)tap * OTOT + obase) * W64 + r];
        }
        for (int e = tid; e < OPW; e += 256) {
            Ald[e] = A[obase + e];
            Bld[e] = B[obase + e];
        }
    }
    __syncthreads();

    const u64* ib = in_bits + (size_t)img * H * W * W64;

    int acc[OPW];
#pragma unroll
    for (int i = 0; i < OPW; ++i) acc[i] = 0;
    int nvalid = 0;

#pragma unroll 1
    for (int dy = 0; dy < 3; ++dy) {
#pragma unroll 1
        for (int dx = 0; dx < 3; ++dx) {
            const int yy = y + dy - 1, xs = x + dx - 1;
            const bool ok = (yy >= 0 && yy < H && xs >= 0 && xs < W);
            nvalid += ok ? 1 : 0;
            u64 wn[W64];
            const u64* q = ib + ((size_t)yy * W + xs) * W64;
#pragma unroll
            for (int k = 0; k < W64; ++k) wn[k] = ok ? q[k] : 0ull;
            const u64* wt = &wl[(dy * 3 + dx) * OPW * W64];
#pragma unroll
            for (int oc = 0; oc < OPW; ++oc) {
                int tp = 0;
#pragma unroll
                for (int k = 0; k < W64; ++k)
                    tp += (int)__popcll(wn[k] ^ wt[oc * W64 + k]);
                acc[oc] += ok ? tp : 0;
            }
        }
    }

    const int basev = nvalid * 64 * W64;
    constexpr int Hp = POOL ? H / 2 : H, Wp = POOL ? W / 2 : W;
    const bool writer = (!POOL) || (((lane & 1) == 0) && ((lane & W) == 0));
    const int py = POOL ? (y >> 1) : y, px = POOL ? (x >> 1) : x;

    u32 cur = 0;
#pragma unroll
    for (int oc = 0; oc < OPW; ++oc) {
        int v = basev - 2 * acc[oc];
        if (POOL) {
            int v2 = max(v, __shfl_xor(v, 1, 64));
            v = max(v2, __shfl_xor(v2, W, 64));
        }
        const double t = fma(Ald[oc], (double)v, Bld[oc]);
        if (LAST) {
            const double hcl = fmin(1.0, fmax(-1.0, t));
            if (writer)
                h5[(((size_t)img * OTOT + obase + oc) * Hp + py) * Wp + px] = (float)hcl;
        } else {
            cur |= (u32)(t < 0.0) << oc;
        }
    }
    if (!LAST && writer) {
        out_bits[((size_t)img * Hp * Wp + (size_t)py * Wp + px) * (OTOT / 32) + (obase >> 5)] = cur;
    }
}

// ---------------------------------------------------------------------------
// FC (f64 accumulate): out[n,10] = h5[n,8192] @ fcw^T + fcb
// ---------------------------------------------------------------------------
__global__ void fc_kernel(const float* __restrict__ h, const float* __restrict__ fcw,
                          const float* __restrict__ fcb, float* __restrict__ out) {
    const int n = blockIdx.x, t = threadIdx.x;
    double acc[10];
#pragma unroll
    for (int j = 0; j < 10; ++j) acc[j] = 0.0;
    const float* hn = h + (size_t)n * 8192;
    for (int k = t; k < 8192; k += 256) {
        double xv = (double)hn[k];
#pragma unroll
        for (int j = 0; j < 10; ++j) acc[j] += xv * (double)fcw[j * 8192 + k];
    }
    __shared__ double red[10][256];
#pragma unroll
    for (int j = 0; j < 10; ++j) red[j][t] = acc[j];
    __syncthreads();
    for (int r = 128; r > 0; r >>= 1) {
        if (t < r) {
#pragma unroll
            for (int j = 0; j < 10; ++j) red[j][t] += red[j][t + r];
        }
        __syncthreads();
    }
    if (t < 10) out[n * 10 + t] = (float)(red[t][0] + (double)fcb[t]);
}

// ===========================================================================
extern "C" void kernel_launch(void* const* d_in, const int* in_sizes, int n_in,
                              void* d_out, int out_size, void* d_ws, size_t ws_size,
                              hipStream_t stream) {
    const float* X = (const float*)d_in[0];
    BnArgs bn;
    PackArgs pk;
    const float* Wt0 = (const float*)d_in[1];
    for (int i = 0; i < 6; ++i) {
        bn.g[i] = (const float*)d_in[2 + 5 * i];
        bn.b[i] = (const float*)d_in[3 + 5 * i];
        bn.m[i] = (const float*)d_in[4 + 5 * i];
        bn.v[i] = (const float*)d_in[5 + 5 * i];
    }
    for (int i = 0; i < 5; ++i) pk.w[i] = (const float*)d_in[1 + 5 * (i + 1)];
    const float* fcw = (const float*)d_in[31];
    const float* fcb = (const float*)d_in[32];
    float* out = (float*)d_out;

    char* ws = (char*)d_ws;
    size_t off = 0;
    auto alloc = [&](size_t bytes) -> void* {
        void* p = ws + off;
        off = (off + bytes + 255) & ~(size_t)255;
        return p;
    };

    // ---- workspace ----
    double* scale_all = (double*)alloc(1792 * sizeof(double));
    double* shift_all = (double*)alloc(1792 * sizeof(double));
    double* A_all     = (double*)alloc(1664 * sizeof(double));
    const size_t WBN[5] = {128ull * 9 * 2, 256ull * 9 * 2, 256ull * 9 * 4,
                           512ull * 9 * 4, 512ull * 9 * 8};
    for (int i = 0; i < 5; ++i) pk.wbt[i] = (u64*)alloc(WBN[i] * sizeof(u64));
    u64* bits0 = (u64*)alloc(256ull * 32 * 32 * 2 * sizeof(u64));
    u64* bits1 = (u64*)alloc(256ull * 16 * 16 * 2 * sizeof(u64));
    u64* bits2 = (u64*)alloc(256ull * 16 * 16 * 4 * sizeof(u64));
    u64* bits3 = (u64*)alloc(256ull * 8 * 8 * 4 * sizeof(u64));
    u64* bits4 = (u64*)alloc(256ull * 8 * 8 * 8 * sizeof(u64));
    float* h5  = (float*)alloc(256ull * 8192 * sizeof(float));

    if (off > ws_size) {
        zero_out<<<dim3((out_size + 255) / 256), dim3(256), 0, stream>>>(out, out_size);
        return;
    }

    const int BOF[6] = {0, 128, 256, 512, 768, 1280};
    const int AOF[5] = {0, 128, 384, 640, 1152};

    // ---- preps ----
    bn_prep_all<<<dim3(7), dim3(256), 0, stream>>>(bn, scale_all, shift_all);
    pack_all<<<dim3(1664), dim3(256), 0, stream>>>(pk, scale_all, A_all);

    // ---- conv0 ----
    conv0_pack<<<dim3(4, 256), dim3(256), 0, stream>>>(
        X, Wt0, scale_all + BOF[0], shift_all + BOF[0], bits0);

    // ---- binconv chain (taps-outer, 32-acc, LDS weights) ----
    // L1: 128->128, 32x32, pool
    bconv4<32, 32, 2, 128, true, false, 4><<<dim3(4, 4, 256), dim3(256), 0, stream>>>(
        bits0, pk.wbt[0], A_all + AOF[0], shift_all + BOF[1], (u32*)bits1, nullptr);
    // L2: 128->256, 16x16
    bconv4<16, 16, 2, 256, false, false, 4><<<dim3(8, 1, 256), dim3(256), 0, stream>>>(
        bits1, pk.wbt[1], A_all + AOF[1], shift_all + BOF[2], (u32*)bits2, nullptr);
    // L3: 256->256, 16x16, pool
    bconv4<16, 16, 4, 256, true, false, 4><<<dim3(8, 1, 256), dim3(256), 0, stream>>>(
        bits2, pk.wbt[2], A_all + AOF[2], shift_all + BOF[3], (u32*)bits3, nullptr);
    // L4: 256->512, 8x8
    bconv4<8, 8, 4, 512, false, false, 4><<<dim3(16, 1, 64), dim3(256), 0, stream>>>(
        bits3, pk.wbt[3], A_all + AOF[3], shift_all + BOF[4], (u32*)bits4, nullptr);
    // L5: 512->512, 8x8, pool -> h5
    bconv4<8, 8, 8, 512, true, true, 4><<<dim3(16, 1, 64), dim3(256), 0, stream>>>(
        bits4, pk.wbt[4], A_all + AOF[4], shift_all + BOF[5], nullptr, h5);

    // ---- FC ----
    fc_kernel<<<dim3(256), dim3(256), 0, stream>>>(h5, fcw, fcb, out);
}